// Round 1
// baseline (851.817 us; speedup 1.0000x reference)
//
#include <hip/hip_runtime.h>
#include <math.h>

// ---------------- geometry ----------------
static constexpr long long SPQ  = 2304;   // Qd*H*W
static constexpr long long CATB = 1024 * SPQ;

// ---------------- ws arena (float offsets) ----------------
static constexpr long long WO_CV1   = 0;
static constexpr long long WO_QKV   = 262144;
static constexpr long long WO_APROJ = 458752;
static constexpr long long WO_PE    = 524288;
static constexpr long long WO_FFN1  = 526592;
static constexpr long long WO_FFN2  = 657664;
static constexpr long long WO_EC    = 788736;
static constexpr long long WO_MPROJ = 821504;
static constexpr long long WO_CV2   = 1116416;
static constexpr long long W_TOTAL  = 1640704;
static constexpr long long OFF_SMALL= W_TOTAL;
static constexpr long long ST_CV1   = OFF_SMALL + 0;
static constexpr long long ST_FFN1  = OFF_SMALL + 1024;
static constexpr long long ST_FFN2  = OFF_SMALL + 2048;
static constexpr long long ST_EC    = OFF_SMALL + 2560;
static constexpr long long ST_MPROJ = OFF_SMALL + 2816;
static constexpr long long ST_CV2   = OFF_SMALL + 3328;
static constexpr long long OFF_GVEC = OFF_SMALL + 8192;   // 256 floats
static constexpr long long OFF_GATE = OFF_SMALL + 8448;   // 8 floats
static constexpr long long OFF_CAT  = OFF_SMALL + 16384;  // [2][1024][2304]
static constexpr long long OFF_A    = OFF_CAT + 2 * CATB; // 2,359,296 floats
static constexpr long long OFF_B    = OFF_A + 2359296;    // 5,308,416 floats (qkv / col)
static constexpr long long OFF_A1   = OFF_B + 3538944;    // a1 (inside B tail)
static constexpr long long OFF_C    = OFF_B + 5308416;    // 1,179,648 floats
static constexpr long long WS_FLOATS= OFF_C + 1179648;    // 15,223,040 (~61 MB)

// ---------------- weight prep: w = m * cos(p) ----------------
struct WPrep {
  const float* m[9];
  const float* p[9];
  float* out;
  int cum[10];
};

__global__ __launch_bounds__(256) void k_wprep(WPrep P) {
  int i = blockIdx.x * 256 + threadIdx.x;
  if (i >= P.cum[9]) return;
  int s = 0;
  while (s < 8 && i >= P.cum[s + 1]) s++;
  int j = i - P.cum[s];
  P.out[i] = P.m[s][j] * cosf(P.p[s][j]);
}

// ---------------- batched GEMM: Y[g][o][m] = sum_k W[o][k] X[g][k][m] (+Add) ----------------
struct GemmP {
  const float* Wt;   // [O][K]
  const float* X;    // base; element (g,k,m) at xOff[g] + k*M + m
  float* Y;          // base; element (g,o,m) at yOff[g] + o*ycs + m
  const float* Add;  // optional; tight: aOff[g] + o*M + m
  long long xOff[8], yOff[8], aOff[8];
  int O, K, M, G, ycs;
};

#define GT_O 64
#define GT_M 64
#define GT_K 16

__global__ __launch_bounds__(256) void k_gemm(GemmP P) {
  const int mt = P.M / GT_M;
  const int ot = P.O / GT_O;
  int bid = blockIdx.x;
  const int g  = bid / (mt * ot);
  const int r  = bid % (mt * ot);
  const int ob = (r / mt) * GT_O;
  const int mb = (r % mt) * GT_M;

  const float* X = P.X + P.xOff[g] + mb;
  __shared__ float sW[GT_K][GT_O];
  __shared__ float sX[GT_K][GT_M + 4];

  const int t  = threadIdx.x;
  const int tm = t % 16;
  const int to = t / 16;

  float acc[4][4] = {};

  for (int k0 = 0; k0 < P.K; k0 += GT_K) {
#pragma unroll
    for (int i = 0; i < 4; i++) {
      int e  = t + i * 256;
      int kk = e % GT_K, oo = e / GT_K;
      sW[kk][oo] = P.Wt[(long long)(ob + oo) * P.K + k0 + kk];
    }
#pragma unroll
    for (int i = 0; i < 4; i++) {
      int e  = t + i * 256;
      int kk = e / GT_M, mm = e % GT_M;
      sX[kk][mm] = X[(long long)(k0 + kk) * P.M + mm];
    }
    __syncthreads();
#pragma unroll
    for (int kk = 0; kk < GT_K; kk++) {
      float a[4], b[4];
#pragma unroll
      for (int i = 0; i < 4; i++) a[i] = sW[kk][to * 4 + i];
#pragma unroll
      for (int j = 0; j < 4; j++) b[j] = sX[kk][tm * 4 + j];
#pragma unroll
      for (int i = 0; i < 4; i++)
#pragma unroll
        for (int j = 0; j < 4; j++) acc[i][j] = fmaf(a[i], b[j], acc[i][j]);
    }
    __syncthreads();
  }

#pragma unroll
  for (int i = 0; i < 4; i++) {
    int o = ob + to * 4 + i;
#pragma unroll
    for (int j = 0; j < 4; j++) {
      int m = mb + tm * 4 + j;
      float v = acc[i][j];
      if (P.Add) v += P.Add[P.aOff[g] + (long long)o * P.M + m];
      P.Y[P.yOff[g] + (long long)o * P.ycs + m] = v;
    }
  }
}

// ---------------- BN stats: per-channel mean/rstd over (G,M) ----------------
__global__ __launch_bounds__(256) void k_bnstats(const float* X, float* stats, int O, int M, int G) {
  int o = blockIdx.x;
  long long om = (long long)O * M;
  float s = 0.f, s2 = 0.f;
  for (int g = 0; g < G; g++) {
    const float* xp = X + g * om + (long long)o * M;
    for (int m = threadIdx.x; m < M; m += 256) {
      float v = xp[m];
      s += v;
      s2 += v * v;
    }
  }
#pragma unroll
  for (int off = 32; off > 0; off >>= 1) {
    s  += __shfl_down(s, off, 64);
    s2 += __shfl_down(s2, off, 64);
  }
  __shared__ float t1[4], t2[4];
  int lane = threadIdx.x & 63, wv = threadIdx.x >> 6;
  if (lane == 0) { t1[wv] = s; t2[wv] = s2; }
  __syncthreads();
  if (threadIdx.x == 0) {
    s  = t1[0] + t1[1] + t1[2] + t1[3];
    s2 = t2[0] + t2[1] + t2[2] + t2[3];
    float n    = (float)(G * M);
    float mean = s / n;
    float var  = s2 / n - mean * mean;
    stats[2 * o]     = mean;
    stats[2 * o + 1] = rsqrtf(var + 1e-5f);
  }
}

// ---------------- BN normalize (+optional add, relu) ----------------
struct NormP {
  const float* X;      // tight [G][O][M]
  const float* stats;  // [O][2]
  float* Y;
  const float* Add;    // tight [G][O][M] or null
  long long yOff[8];
  int O, M, G, ycs, relu;
};

__global__ __launch_bounds__(256) void k_bnnorm(NormP P) {
  long long total = (long long)P.G * P.O * P.M;
  long long idx = (long long)blockIdx.x * 256 + threadIdx.x;
  if (idx >= total) return;
  int m = (int)(idx % P.M);
  int o = (int)((idx / P.M) % P.O);
  int g = (int)(idx / ((long long)P.M * P.O));
  float v = P.X[idx];
  v = (v - P.stats[2 * o]) * P.stats[2 * o + 1];
  if (P.Add) v += P.Add[idx];
  if (P.relu) v = fmaxf(v, 0.f);
  P.Y[P.yOff[g] + (long long)o * P.ycs + m] = v;
}

// ---------------- depthwise 3x3 pe conv + residual: r = dw3x3(b) + b ----------------
__global__ __launch_bounds__(256) void k_pe(const float* cat, const float* wpe, float* r) {
  int idx = blockIdx.x * 256 + threadIdx.x;
  if (idx >= 2 * 256 * 2304) return;
  int m   = idx % 2304;
  int cch = (idx / 2304) % 256;
  int b   = idx / (2304 * 256);
  int hw = m % 576, q = m / 576;
  int h = hw / 24, w = hw % 24;
  const float* src = cat + (long long)b * CATB + (long long)(256 + cch) * SPQ + q * 576;
  float acc = src[hw];  // residual (+x)
#pragma unroll
  for (int kh = 0; kh < 3; kh++) {
    int hh = h + kh - 1;
    if (hh < 0 || hh > 23) continue;
#pragma unroll
    for (int kw = 0; kw < 3; kw++) {
      int ww = w + kw - 1;
      if (ww < 0 || ww > 23) continue;
      acc += wpe[cch * 9 + kh * 3 + kw] * src[hh * 24 + ww];
    }
  }
  r[idx] = acc;
}

// ---------------- flash attention: 128 units of (N=576, kd=16) ----------------
#define ATM 192
__global__ __launch_bounds__(64) void k_attn(const float* qkv, float* ao) {
  int bid = blockIdx.x;
  int nt = bid % 9;
  int u  = bid / 9;
  int qd = u % 4; u /= 4;
  int head = u % 16;
  int b    = u / 16;
  int n = nt * 64 + threadIdx.x;

  long long base = (long long)b * 768 * SPQ + qd * 576;
  const float* Qp = qkv + base + (long long)(head * 16) * SPQ;
  const float* Kp = qkv + base + (long long)(256 + head * 16) * SPQ;
  const float* Vp = qkv + base + (long long)(512 + head * 16) * SPQ;

  float qv[16];
#pragma unroll
  for (int c = 0; c < 16; c++) qv[c] = Qp[(long long)c * SPQ + n] * 0.25f;

  __shared__ float sK[16][ATM];
  __shared__ float sV[16][ATM];

  float mx = -1e30f, sum = 0.f;
  float o[16] = {};

  for (int m0 = 0; m0 < 576; m0 += ATM) {
    __syncthreads();
    for (int e = threadIdx.x; e < 16 * ATM; e += 64) {
      int c = e / ATM, mm = e % ATM;
      sK[c][mm] = Kp[(long long)c * SPQ + m0 + mm];
      sV[c][mm] = Vp[(long long)c * SPQ + m0 + mm];
    }
    __syncthreads();
    for (int mm = 0; mm < ATM; mm++) {
      float s = 0.f;
#pragma unroll
      for (int c = 0; c < 16; c++) s = fmaf(qv[c], sK[c][mm], s);
      float nm   = fmaxf(mx, s);
      float corr = __expf(mx - nm);
      float pv   = __expf(s - nm);
      sum = sum * corr + pv;
#pragma unroll
      for (int d = 0; d < 16; d++) o[d] = o[d] * corr + pv * sV[d][mm];
      mx = nm;
    }
  }
  float inv = 1.f / sum;
  long long ob = (long long)b * 256 * SPQ + (long long)(head * 16) * SPQ + qd * 576 + n;
#pragma unroll
  for (int d = 0; d < 16; d++) ao[ob + (long long)d * SPQ] = o[d] * inv;
}

// ---------------- guide linear: g[b][e] = guide[b]·gl_w[e] + gl_b[e] ----------------
__global__ __launch_bounds__(256) void k_guide(const float* guide, const float* glw,
                                               const float* glb, float* g) {
  int t = threadIdx.x;
  if (t >= 256) return;
  int b = t / 128, e = t % 128;
  float s = glb[e];
  const float* gr = guide + b * 512;
  const float* wr = glw + e * 512;
  for (int c = 0; c < 512; c++) s = fmaf(gr[c], wr[c], s);
  g[t] = s;
}

// ---------------- gate: gates[b,q] = sigmoid( sum_{c,hw} e*g / sqrt(128*576) ) ----------------
__global__ __launch_bounds__(256) void k_gate(const float* e, const float* g, float* gates) {
  int bq = blockIdx.x;
  int b = bq >> 2, q = bq & 3;
  float s = 0.f;
  for (int c = 0; c < 128; c++) {
    float gc = g[b * 128 + c];
    const float* row = e + (long long)b * 128 * SPQ + (long long)c * SPQ + q * 576;
    for (int m = threadIdx.x; m < 576; m += 256) s = fmaf(row[m], gc, s);
  }
#pragma unroll
  for (int off = 32; off > 0; off >>= 1) s += __shfl_down(s, off, 64);
  __shared__ float t1[4];
  int lane = threadIdx.x & 63, wv = threadIdx.x >> 6;
  if (lane == 0) t1[wv] = s;
  __syncthreads();
  if (threadIdx.x == 0) {
    s = t1[0] + t1[1] + t1[2] + t1[3];
    float a = s / sqrtf(73728.0f);
    gates[bq] = 1.f / (1.f + expf(-a));
  }
}

// ---------------- im2col (3x3, pad 1) with gate scale ----------------
__global__ __launch_bounds__(256) void k_im2col(const float* e, const float* gates, float* col) {
  long long idx = (long long)blockIdx.x * 256 + threadIdx.x;
  if (idx >= 8LL * 1152 * 576) return;
  int n = (int)(idx % 576);
  int k = (int)((idx / 576) % 1152);
  int g = (int)(idx / (576 * 1152));
  int b = g >> 2, q = g & 3;
  int c = k / 9, kk = k % 9;
  int h = n / 24 + kk / 3 - 1;
  int w = n % 24 + kk % 3 - 1;
  float v = 0.f;
  if (h >= 0 && h < 24 && w >= 0 && w < 24)
    v = gates[g] * e[(long long)b * 128 * SPQ + (long long)c * SPQ + q * 576 + h * 24 + w];
  col[idx] = v;
}

// ---------------- host ----------------
extern "C" void kernel_launch(void* const* d_in, const int* in_sizes, int n_in,
                              void* d_out, int out_size, void* d_ws, size_t ws_size,
                              hipStream_t stream) {
  if (ws_size < (size_t)WS_FLOATS * 4) return;  // need ~61 MB scratch
  float* ws = (float*)d_ws;
  float* out = (float*)d_out;
  const float* x     = (const float*)d_in[0];
  const float* guide = (const float*)d_in[1];
  const float* glw   = (const float*)d_in[16];
  const float* glb   = (const float*)d_in[17];

  // 1. weights: w = m * cos(p), packed arena
  {
    WPrep p;
    const int mi[9] = {2, 4, 6, 8, 10, 12, 14, 18, 20};
    const int sz[9] = {262144, 196608, 65536, 2304, 131072, 131072, 32768, 294912, 524288};
    int c = 0;
    for (int i = 0; i < 9; i++) {
      p.m[i] = (const float*)d_in[mi[i]];
      p.p[i] = (const float*)d_in[mi[i] + 1];
      p.cum[i] = c;
      c += sz[i];
    }
    p.cum[9] = c;
    p.out = ws;
    k_wprep<<<(c + 255) / 256, 256, 0, stream>>>(p);
  }

  auto gemm = [&](long long wOff, int O, int K, int M, int G,
                  const float* X, long long xs, long long xa,
                  float* Y, long long ys, long long ya, int ycs,
                  const float* Add, long long as_) {
    GemmP p;
    p.Wt = ws + wOff; p.X = X; p.Y = Y; p.Add = Add;
    p.O = O; p.K = K; p.M = M; p.G = G; p.ycs = ycs;
    for (int g = 0; g < 8; g++) {
      int gg = (g < G) ? g : 0;
      p.xOff[g] = (long long)gg * xs + xa;
      p.yOff[g] = (long long)gg * ys + ya;
      p.aOff[g] = (long long)gg * as_;
    }
    k_gemm<<<G * (O / 64) * (M / 64), 256, 0, stream>>>(p);
  };
  auto stats = [&](const float* X, long long stOff, int O, int M, int G) {
    k_bnstats<<<O, 256, 0, stream>>>(X, ws + stOff, O, M, G);
  };
  auto norm = [&](const float* X, long long stOff, float* Y, const long long* yOffs,
                  int O, int M, int G, int ycs, int relu, const float* Add) {
    NormP p;
    p.X = X; p.stats = ws + stOff; p.Y = Y; p.Add = Add;
    p.O = O; p.M = M; p.G = G; p.ycs = ycs; p.relu = relu;
    for (int g = 0; g < 8; g++) p.yOff[g] = yOffs[(g < G) ? g : 0];
    long long total = (long long)G * O * M;
    k_bnnorm<<<(int)((total + 255) / 256), 256, 0, stream>>>(p);
  };

  // 2-4. cv1 -> bn -> relu -> cat[0..511]
  gemm(WO_CV1, 512, 512, 2304, 2, x, 512 * SPQ, 0, ws + OFF_A, 512 * SPQ, 0, 2304, nullptr, 0);
  stats(ws + OFF_A, ST_CV1, 512, 2304, 2);
  { long long yo[2] = {0, CATB};
    norm(ws + OFF_A, ST_CV1, ws + OFF_CAT, yo, 512, 2304, 2, 2304, 1, nullptr); }

  // 5. qkv = Wqkv * b
  gemm(WO_QKV, 768, 256, 2304, 2, ws + OFF_CAT, CATB, 256 * SPQ,
       ws + OFF_B, 768 * SPQ, 0, 2304, nullptr, 0);
  // 6. flash attention -> attnout (OFF_A)
  k_attn<<<1152, 64, 0, stream>>>(ws + OFF_B, ws + OFF_A);
  // 7. r = pe(b) + b -> OFF_C
  k_pe<<<(2 * 256 * 2304 + 255) / 256, 256, 0, stream>>>(ws + OFF_CAT, ws + WO_PE, ws + OFF_C);
  // 8. a1 = aproj(attnout) + r -> OFF_A1
  gemm(WO_APROJ, 256, 256, 2304, 2, ws + OFF_A, 256 * SPQ, 0,
       ws + OFF_A1, 256 * SPQ, 0, 2304, ws + OFF_C, 256 * SPQ);

  // 9-11. ffn1 -> bn -> relu (in place in OFF_A)
  gemm(WO_FFN1, 512, 256, 2304, 2, ws + OFF_A1, 256 * SPQ, 0,
       ws + OFF_A, 512 * SPQ, 0, 2304, nullptr, 0);
  stats(ws + OFF_A, ST_FFN1, 512, 2304, 2);
  { long long yo[2] = {0, 512 * SPQ};
    norm(ws + OFF_A, ST_FFN1, ws + OFF_A, yo, 512, 2304, 2, 2304, 1, nullptr); }

  // 12-14. ffn2 -> bn -> (+a1) -> cat[512..767]  (p tensor)
  gemm(WO_FFN2, 256, 512, 2304, 2, ws + OFF_A, 512 * SPQ, 0,
       ws + OFF_C, 256 * SPQ, 0, 2304, nullptr, 0);
  stats(ws + OFF_C, ST_FFN2, 256, 2304, 2);
  { long long yo[2] = {512 * SPQ, CATB + 512 * SPQ};
    norm(ws + OFF_C, ST_FFN2, ws + OFF_CAT, yo, 256, 2304, 2, 2304, 0, ws + OFF_A1); }

  // 15-17. ec -> bn -> relu (in place in OFF_C)
  gemm(WO_EC, 128, 256, 2304, 2, ws + OFF_CAT, CATB, 512 * SPQ,
       ws + OFF_C, 128 * SPQ, 0, 2304, nullptr, 0);
  stats(ws + OFF_C, ST_EC, 128, 2304, 2);
  { long long yo[2] = {0, 128 * SPQ};
    norm(ws + OFF_C, ST_EC, ws + OFF_C, yo, 128, 2304, 2, 2304, 1, nullptr); }

  // 18-19. guide linear, sigmoid gates
  k_guide<<<1, 256, 0, stream>>>(guide, glw, glb, ws + OFF_GVEC);
  k_gate<<<8, 256, 0, stream>>>(ws + OFF_C, ws + OFF_GVEC, ws + OFF_GATE);

  // 20-23. im2col(gated e) -> mproj GEMM -> bn -> relu -> cat[768..1023]
  k_im2col<<<(int)((8LL * 1152 * 576 + 255) / 256), 256, 0, stream>>>(
      ws + OFF_C, ws + OFF_GATE, ws + OFF_B);
  gemm(WO_MPROJ, 256, 1152, 576, 8, ws + OFF_B, 1152 * 576, 0,
       ws + OFF_A, 256 * 576, 0, 576, nullptr, 0);
  stats(ws + OFF_A, ST_MPROJ, 256, 576, 8);
  { long long yo[8];
    for (int g = 0; g < 8; g++) yo[g] = (long long)(g / 4) * CATB + 768 * SPQ + (g % 4) * 576;
    norm(ws + OFF_A, ST_MPROJ, ws + OFF_CAT, yo, 256, 576, 8, 2304, 1, nullptr); }

  // 24-26. cv2 -> bn -> relu -> out
  gemm(WO_CV2, 512, 1024, 2304, 2, ws + OFF_CAT, CATB, 0,
       ws + OFF_A, 512 * SPQ, 0, 2304, nullptr, 0);
  stats(ws + OFF_A, ST_CV2, 512, 2304, 2);
  { long long yo[2] = {0, 512 * SPQ};
    norm(ws + OFF_A, ST_CV2, out, yo, 512, 2304, 2, 2304, 1, nullptr); }
}

// Round 2
// 469.481 us; speedup vs baseline: 1.8144x; 1.8144x over previous
//
#include <hip/hip_runtime.h>
#include <math.h>

typedef __bf16 bf16x8 __attribute__((ext_vector_type(8)));
typedef float f32x4 __attribute__((ext_vector_type(4)));
typedef unsigned short u16;
typedef unsigned int u32;

__device__ __forceinline__ u16 f2bf(float f) {
  u32 u = __float_as_uint(f);
  u32 r = u + 0x7FFF + ((u >> 16) & 1);
  return (u16)(r >> 16);
}
__device__ __forceinline__ float bf2f(u16 h) { return __uint_as_float(((u32)h) << 16); }

// ---------------- arena (byte offsets) ----------------
static constexpr size_t OB_WBF = 0;                       // 1,638,400 u16
static constexpr size_t OB_WPE = 3276800;                 // 2304 f32
static constexpr size_t OB_ST  = 3286016;                 // 6 x 4096B stats
static constexpr size_t OB_GV  = 3310592;                 // 256 f32
static constexpr size_t OB_GT  = 3311616;                 // 8 f32
static constexpr size_t OB_CAT = 3311872;                 // bf16 [2][2304][1024]
static constexpr size_t OB_YA  = OB_CAT + 9437184;        // f32 gemm out (max 9.4MB)
static constexpr size_t OB_U1  = OB_YA + 9437184;         // xbf16 -> a1f f32 (4.7MB)
static constexpr size_t OB_U2  = OB_U1 + 4718592;         // qkv f32 (14.2MB) -> colb+ef
static constexpr size_t OB_U3  = OB_U2 + 14155776;        // rf f32 -> hb bf16 (4.7MB)
static constexpr size_t OB_AOB = OB_U3 + 4718592;         // attn out bf16 (2.36MB)
static constexpr size_t OB_A1B = OB_AOB + 2359296;        // a1 bf16 (2.36MB)
static constexpr size_t WS_TOTAL = OB_A1B + 2359296;      // ~50.5MB

// ---------------- weight prep: w = m*cos(p) -> bf16 (mproj tap-major remap) ----------------
struct WPrepP {
  const float* m[8]; const float* p[8];
  u16* out; const float* pem; const float* pep; float* peout;
  int cum[9];
};
__global__ __launch_bounds__(256) void k_wprep(WPrepP P) {
  int i = blockIdx.x * 256 + threadIdx.x;
  if (i < 2304) P.peout[i] = P.pem[i] * cosf(P.pep[i]);
  if (i >= P.cum[8]) return;
  int s = 0;
  while (s < 7 && i >= P.cum[s + 1]) s++;
  int j = i - P.cum[s];
  int src = j;
  if (s == 6) {  // mproj: out[o][kk*128+cc] <- in[(o*128+cc)*9+kk]
    int o = j / 1152, r = j % 1152, kk = r >> 7, cc = r & 127;
    src = (o * 128 + cc) * 9 + kk;
  }
  P.out[i] = f2bf(P.m[s][src] * cosf(P.p[s][src]));
}

// ---------------- x transpose: [b][c][q][hw] f32 -> [b][q*576+hw][c] bf16 ----------------
__global__ __launch_bounds__(256) void k_xpose(const float* x, u16* xb) {
  int bid = blockIdx.x;
  int mt = bid % 18; bid /= 18;
  int ct = bid % 16; bid /= 16;
  int q = bid & 3, b = bid >> 2;
  __shared__ float tile[32][33];
  int tj = threadIdx.x & 31, ti = threadIdx.x >> 5;
  const float* xp = x + (((size_t)(b * 512 + ct * 32) * 4 + q) * 576) + mt * 32;
#pragma unroll
  for (int ii = 0; ii < 4; ii++)
    tile[ti + ii * 8][tj] = xp[(size_t)(ti + ii * 8) * 4 * 576 + tj];
  __syncthreads();
  u16* yp = xb + ((size_t)b * 2304 + q * 576 + mt * 32) * 512 + ct * 32;
#pragma unroll
  for (int mm = 0; mm < 4; mm++)
    yp[(size_t)(mm * 8 + ti) * 512 + tj] = f2bf(tile[tj][mm * 8 + ti]);
}

// ---------------- MFMA GEMM: Y[g][m][o] = sum_k W[o][k] X[g][m][k] ----------------
struct GemmP {
  const u16* W; const u16* X; float* Y; const float* Add; u16* Yb;
  long long xOff[8];
  int lda, O, K, M, G;
};

template <int BM, int NWO, int WO, int WM>
__global__ __launch_bounds__(256) void k_gemm(GemmP P) {
  constexpr int FO = WO / 16, FM = WM / 16;
  __shared__ __align__(16) char lds[16384 + BM * 128];
  const int mt = P.M / BM;
  const int ot = P.O >> 7;
  int bid = blockIdx.x;
  const int g = bid / (mt * ot);
  const int rr = bid % (mt * ot);
  const int ob = (rr / mt) << 7;
  const int mb = (rr % mt) * BM;
  const int t = threadIdx.x, lane = t & 63, wave = t >> 6;
  const int wo = (wave % NWO) * WO, wm = (wave / NWO) * WM;
  const u16* Wp = P.W + (size_t)ob * P.K;
  const u16* Xp = P.X + P.xOff[g] + (size_t)mb * P.lda;

  f32x4 acc[FO][FM] = {};

  for (int k0 = 0; k0 < P.K; k0 += 64) {
#pragma unroll
    for (int i = 0; i < 4; i++) {  // A: 128 rows x 8 kg
      int c = t + i * 256;
      int row = c >> 3, kg = c & 7;
      *(uint4*)&lds[((row << 3) + (kg ^ (row & 7))) << 4] =
          *(const uint4*)(Wp + (size_t)row * P.K + k0 + kg * 8);
    }
#pragma unroll
    for (int i = 0; i < BM * 8 / 256; i++) {  // B: BM rows x 8 kg
      int c = t + i * 256;
      int row = c >> 3, kg = c & 7;
      *(uint4*)&lds[16384 + (((row << 3) + (kg ^ (row & 7))) << 4)] =
          *(const uint4*)(Xp + (size_t)row * P.lda + k0 + kg * 8);
    }
    __syncthreads();
#pragma unroll
    for (int kk = 0; kk < 2; kk++) {
      int kgl = kk * 4 + (lane >> 4);
      bf16x8 af[FO], bfm[FM];
#pragma unroll
      for (int fo = 0; fo < FO; fo++) {
        int row = wo + fo * 16 + (lane & 15);
        af[fo] = *(bf16x8*)&lds[((row << 3) + (kgl ^ (row & 7))) << 4];
      }
#pragma unroll
      for (int fm = 0; fm < FM; fm++) {
        int row = wm + fm * 16 + (lane & 15);
        bfm[fm] = *(bf16x8*)&lds[16384 + (((row << 3) + (kgl ^ (row & 7))) << 4)];
      }
#pragma unroll
      for (int fo = 0; fo < FO; fo++)
#pragma unroll
        for (int fm = 0; fm < FM; fm++)
          acc[fo][fm] = __builtin_amdgcn_mfma_f32_16x16x32_bf16(af[fo], bfm[fm], acc[fo][fm], 0, 0, 0);
    }
    __syncthreads();
  }

  size_t ybase = (size_t)g * P.M * P.O;
#pragma unroll
  for (int fo = 0; fo < FO; fo++) {
    int ow = ob + wo + fo * 16 + ((lane >> 4) << 2);
#pragma unroll
    for (int fm = 0; fm < FM; fm++) {
      int m = mb + wm + fm * 16 + (lane & 15);
      f32x4 v = acc[fo][fm];
      size_t off = ybase + (size_t)m * P.O + ow;
      if (P.Add) v += *(const f32x4*)&P.Add[off];
      *(f32x4*)&P.Y[off] = v;
      if (P.Yb) {
        ushort4 r;
        r.x = f2bf(v[0]); r.y = f2bf(v[1]); r.z = f2bf(v[2]); r.w = f2bf(v[3]);
        *(ushort4*)&P.Yb[off] = r;
      }
    }
  }
}

// ---------------- BN stats (atomic partials over rows of [rows][O]) ----------------
__global__ __launch_bounds__(256) void k_stats(const float* X, float* st, int O, int rows) {
  float s0 = 0, q0 = 0, s1 = 0, q1 = 0;
  int c0 = threadIdx.x, c1 = threadIdx.x + 256;
  bool h0 = c0 < O, h1 = c1 < O;
  for (int r = blockIdx.x; r < rows; r += gridDim.x) {
    const float* xp = X + (size_t)r * O;
    if (h0) { float v = xp[c0]; s0 += v; q0 += v * v; }
    if (h1) { float v = xp[c1]; s1 += v; q1 += v * v; }
  }
  if (h0) { atomicAdd(&st[2 * c0], s0); atomicAdd(&st[2 * c0 + 1], q0); }
  if (h1) { atomicAdd(&st[2 * c1], s1); atomicAdd(&st[2 * c1 + 1], q1); }
}
__global__ void k_finstats(float* st, int O, float n) {
  int c = blockIdx.x * 64 + threadIdx.x;
  if (c >= O) return;
  float mean = st[2 * c] / n;
  float var = st[2 * c + 1] / n - mean * mean;
  st[2 * c] = mean;
  st[2 * c + 1] = rsqrtf(var + 1e-5f);
}

// ---------------- BN normalize (+add, relu) -> bf16 and/or f32 ----------------
struct NormP {
  const float* X; const float* st; const float* Add;
  u16* Yb; float* Yf;
  long long ybOff[8];
  int ldyb, O, G, M, relu;
};
__global__ __launch_bounds__(256) void k_norm(NormP P) {
  int O4 = P.O >> 2;
  long long idx = (long long)blockIdx.x * 256 + threadIdx.x;
  if (idx >= (long long)P.G * P.M * O4) return;
  int c4 = (int)(idx % O4);
  long long gm = idx / O4;
  int m = (int)(gm % P.M);
  int g = (int)(gm / P.M);
  size_t off = (size_t)gm * P.O + c4 * 4;
  f32x4 v = *(const f32x4*)&P.X[off];
#pragma unroll
  for (int j = 0; j < 4; j++) {
    int c = c4 * 4 + j;
    v[j] = (v[j] - P.st[2 * c]) * P.st[2 * c + 1];
  }
  if (P.Add) v += *(const f32x4*)&P.Add[off];
  if (P.relu) {
#pragma unroll
    for (int j = 0; j < 4; j++) v[j] = fmaxf(v[j], 0.f);
  }
  if (P.Yb) {
    ushort4 r;
    r.x = f2bf(v[0]); r.y = f2bf(v[1]); r.z = f2bf(v[2]); r.w = f2bf(v[3]);
    *(ushort4*)(P.Yb + P.ybOff[g] + (size_t)m * P.ldyb + c4 * 4) = r;
  }
  if (P.Yf) *(f32x4*)&P.Yf[off] = v;
}

// ---------------- final norm with transpose to [b][o][q][hw] f32 ----------------
__global__ __launch_bounds__(256) void k_normT(const float* X, const float* st, float* out) {
  int idx = blockIdx.x * 256 + threadIdx.x;  // (b*512+o)*576 + m4
  if (idx >= 2 * 512 * 576) return;
  int m4 = idx % 576;
  int bo = idx / 576;
  int o = bo & 511, b = bo >> 9;
  float mean = st[2 * o], rs = st[2 * o + 1];
  f32x4 v;
#pragma unroll
  for (int j = 0; j < 4; j++) {
    float x = X[((size_t)b * 2304 + m4 * 4 + j) * 512 + o];
    v[j] = fmaxf((x - mean) * rs, 0.f);
  }
  *(f32x4*)&out[(size_t)bo * 2304 + m4 * 4] = v;
}

// ---------------- depthwise 3x3 pe + residual: rf[g][m][c] = dw(b)+b ----------------
__global__ __launch_bounds__(256) void k_pe(const u16* catb, const float* wpe, float* rf) {
  int idx = blockIdx.x * 256 + threadIdx.x;  // (g*2304+m)*64 + c4
  if (idx >= 2 * 2304 * 64) return;
  int c4 = idx & 63;
  int gm = idx >> 6;
  int m = gm % 2304, g = gm / 2304;
  int q = m / 576, hw = m % 576, h = hw / 24, w = hw % 24;
  const u16* base = catb + (size_t)g * 2304 * 1024 + 256 + c4 * 4;
  float acc[4];
  {
    ushort4 cv = *(const ushort4*)(base + (size_t)m * 1024);
    acc[0] = bf2f(cv.x); acc[1] = bf2f(cv.y); acc[2] = bf2f(cv.z); acc[3] = bf2f(cv.w);
  }
#pragma unroll
  for (int kh = 0; kh < 3; kh++) {
    int hh = h + kh - 1;
    if (hh < 0 || hh > 23) continue;
#pragma unroll
    for (int kw = 0; kw < 3; kw++) {
      int ww = w + kw - 1;
      if (ww < 0 || ww > 23) continue;
      ushort4 cv = *(const ushort4*)(base + (size_t)(q * 576 + hh * 24 + ww) * 1024);
      float tap[4] = {bf2f(cv.x), bf2f(cv.y), bf2f(cv.z), bf2f(cv.w)};
#pragma unroll
      for (int j = 0; j < 4; j++)
        acc[j] = fmaf(wpe[(c4 * 4 + j) * 9 + kh * 3 + kw], tap[j], acc[j]);
    }
  }
  f32x4 v = {acc[0], acc[1], acc[2], acc[3]};
  *(f32x4*)&rf[(size_t)gm * 256 + c4 * 4] = v;
}

// ---------------- attention: no-max softmax (scores tiny), 4-way key split ----------------
#define KT 48
__global__ __launch_bounds__(256) void k_attn(const float* qkv, u16* ao) {
  int bid = blockIdx.x;
  int qt = bid % 9; bid /= 9;
  int qd = bid & 3; bid >>= 2;
  int head = bid & 15, b = bid >> 4;
  int lane = threadIdx.x & 63, wv = threadIdx.x >> 6;
  int n = qt * 64 + lane;
  const float* Qb = qkv + ((size_t)b * 2304 + qd * 576) * 768;

  float qv[16];
  {
    const float* qp = Qb + (size_t)n * 768 + head * 16;
#pragma unroll
    for (int c = 0; c < 16; c++) qv[c] = qp[c] * 0.25f;
  }

  __shared__ __align__(16) char shm[24576];
  float(*sK)[KT][16] = (float(*)[KT][16])shm;
  float(*sV)[KT][16] = (float(*)[KT][16])(shm + 12288);

  float sum = 0.f;
  float o[16];
#pragma unroll
  for (int d = 0; d < 16; d++) o[d] = 0.f;

  int k0w = wv * 144;
  for (int tile = 0; tile < 3; tile++) {
    int k0 = k0w + tile * KT;
    __syncthreads();
#pragma unroll
    for (int i = 0; i < 3; i++) {
      int cc = lane + i * 64;
      int mm = cc >> 2, c4 = cc & 3;
      const float* kp = Qb + (size_t)(k0 + mm) * 768 + 256 + head * 16 + c4 * 4;
      *(f32x4*)&sK[wv][mm][c4 * 4] = *(const f32x4*)kp;
      *(f32x4*)&sV[wv][mm][c4 * 4] = *(const f32x4*)(kp + 256);
    }
    __syncthreads();
    for (int mm = 0; mm < KT; mm++) {
      const float* kr = &sK[wv][mm][0];
      float s = 0.f;
#pragma unroll
      for (int c = 0; c < 16; c++) s = fmaf(qv[c], kr[c], s);
      float pv = __expf(s);
      sum += pv;
      const float* vr = &sV[wv][mm][0];
#pragma unroll
      for (int d = 0; d < 16; d++) o[d] = fmaf(pv, vr[d], o[d]);
    }
  }
  __syncthreads();
  float(*ps)[64] = (float(*)[64])shm;
  float(*po)[64][17] = (float(*)[64][17])(shm + 1024);
  ps[wv][lane] = sum;
#pragma unroll
  for (int d = 0; d < 16; d++) po[wv][lane][d] = o[d];
  __syncthreads();
  if (threadIdx.x < 64) {
    float S = 0.f;
    float oo[16];
#pragma unroll
    for (int d = 0; d < 16; d++) oo[d] = 0.f;
#pragma unroll
    for (int w = 0; w < 4; w++) {
      S += ps[w][lane];
#pragma unroll
      for (int d = 0; d < 16; d++) oo[d] += po[w][lane][d];
    }
    float inv = 1.f / S;
    u16* op = ao + ((size_t)b * 2304 + qd * 576 + n) * 256 + head * 16;
#pragma unroll
    for (int d4 = 0; d4 < 4; d4++) {
      ushort4 r;
      r.x = f2bf(oo[d4 * 4 + 0] * inv);
      r.y = f2bf(oo[d4 * 4 + 1] * inv);
      r.z = f2bf(oo[d4 * 4 + 2] * inv);
      r.w = f2bf(oo[d4 * 4 + 3] * inv);
      *(ushort4*)(op + d4 * 4) = r;
    }
  }
}

// ---------------- guide linear ----------------
__global__ void k_guide(const float* guide, const float* glw, const float* glb, float* g) {
  int t = threadIdx.x;
  int b = t >> 7, e = t & 127;
  float s = glb[e];
  const float* gr = guide + b * 512;
  const float* wr = glw + e * 512;
  for (int c = 0; c < 512; c++) s = fmaf(gr[c], wr[c], s);
  g[t] = s;
}

// ---------------- gate: sigmoid(sum e*g / sqrt(128*576)) per (b,q) ----------------
__global__ __launch_bounds__(256) void k_gate(const float* ef, const float* g, float* gates) {
  int bq = blockIdx.x;
  int b = bq >> 2, q = bq & 3;
  int c = threadIdx.x & 127, h2 = threadIdx.x >> 7;
  float gc = g[b * 128 + c];
  float s = 0.f;
  for (int hw = h2; hw < 576; hw += 2)
    s += ef[((size_t)b * 2304 + q * 576 + hw) * 128 + c] * gc;
#pragma unroll
  for (int off = 32; off > 0; off >>= 1) s += __shfl_down(s, off, 64);
  __shared__ float t1[4];
  int lane = threadIdx.x & 63, wv2 = threadIdx.x >> 6;
  if (lane == 0) t1[wv2] = s;
  __syncthreads();
  if (threadIdx.x == 0) {
    s = t1[0] + t1[1] + t1[2] + t1[3];
    float a = s / sqrtf(73728.0f);
    gates[bq] = 1.f / (1.f + expf(-a));
  }
}

// ---------------- im2col (gated, tap-major k) -> bf16 col [g][n][kk*128+c] ----------------
__global__ __launch_bounds__(256) void k_im2col(const float* ef, const float* gates, u16* col) {
  int idx = blockIdx.x * 256 + threadIdx.x;  // (g*576+n)*9+kk
  if (idx >= 8 * 576 * 9) return;
  int kk = idx % 9;
  int gn = idx / 9;
  int n = gn % 576, g = gn / 576;
  int b = g >> 2, q = g & 3;
  int h = n / 24 + kk / 3 - 1, w = n % 24 + kk % 3 - 1;
  u16* cp = col + (size_t)gn * 1152 + kk * 128;
  if (h < 0 || h > 23 || w < 0 || w > 23) {
    ushort4 z = {0, 0, 0, 0};
#pragma unroll
    for (int c4 = 0; c4 < 32; c4++) *(ushort4*)&cp[c4 * 4] = z;
    return;
  }
  float gt = gates[g];
  const float* ep = ef + ((size_t)b * 2304 + q * 576 + h * 24 + w) * 128;
  for (int c4 = 0; c4 < 32; c4++) {
    f32x4 v = *(const f32x4*)&ep[c4 * 4];
    ushort4 r;
    r.x = f2bf(v[0] * gt); r.y = f2bf(v[1] * gt);
    r.z = f2bf(v[2] * gt); r.w = f2bf(v[3] * gt);
    *(ushort4*)&cp[c4 * 4] = r;
  }
}

// ---------------- host ----------------
extern "C" void kernel_launch(void* const* d_in, const int* in_sizes, int n_in,
                              void* d_out, int out_size, void* d_ws, size_t ws_size,
                              hipStream_t stream) {
  if (ws_size < WS_TOTAL) return;
  char* ws = (char*)d_ws;
  u16* WB = (u16*)(ws + OB_WBF);
  float* WPE = (float*)(ws + OB_WPE);
  float* STB = (float*)(ws + OB_ST);
  float* GV = (float*)(ws + OB_GV);
  float* GT = (float*)(ws + OB_GT);
  u16* CATB = (u16*)(ws + OB_CAT);
  float* YA = (float*)(ws + OB_YA);
  u16* XBF = (u16*)(ws + OB_U1);
  float* A1F = (float*)(ws + OB_U1);
  float* QKVF = (float*)(ws + OB_U2);
  u16* COLB = (u16*)(ws + OB_U2);
  float* EF = (float*)(ws + OB_U2 + 10616832);
  float* RF = (float*)(ws + OB_U3);
  u16* HB = (u16*)(ws + OB_U3);
  u16* AOB = (u16*)(ws + OB_AOB);
  u16* A1B = (u16*)(ws + OB_A1B);
  float* out = (float*)d_out;
  const float* x = (const float*)d_in[0];
  const float* guide = (const float*)d_in[1];
  const float* glw = (const float*)d_in[16];
  const float* glb = (const float*)d_in[17];

  hipMemsetAsync(ws + OB_ST, 0, 24576, stream);

  {  // weights
    WPrepP p;
    const int mi[8] = {2, 4, 6, 10, 12, 14, 18, 20};
    const int sz[8] = {262144, 196608, 65536, 131072, 131072, 32768, 294912, 524288};
    int c = 0;
    for (int i = 0; i < 8; i++) {
      p.m[i] = (const float*)d_in[mi[i]];
      p.p[i] = (const float*)d_in[mi[i] + 1];
      p.cum[i] = c;
      c += sz[i];
    }
    p.cum[8] = c;
    p.out = WB;
    p.pem = (const float*)d_in[8];
    p.pep = (const float*)d_in[9];
    p.peout = WPE;
    k_wprep<<<(c + 255) / 256, 256, 0, stream>>>(p);
  }
  k_xpose<<<2304, 256, 0, stream>>>(x, XBF);

  auto gemm = [&](int bm64, size_t wOff, int O, int K, int M, int G,
                  const u16* X, long long xs, long long xadd, int lda,
                  float* Y, const float* Add, u16* Yb) {
    GemmP p;
    p.W = WB + wOff; p.X = X; p.Y = Y; p.Add = Add; p.Yb = Yb;
    p.lda = lda; p.O = O; p.K = K; p.M = M; p.G = G;
    for (int g = 0; g < 8; g++) p.xOff[g] = (long long)(g < G ? g : 0) * xs + xadd;
    if (bm64) {
      int grid = G * (O / 128) * (M / 64);
      k_gemm<64, 4, 32, 64><<<grid, 256, 0, stream>>>(p);
    } else {
      int grid = G * (O / 128) * (M / 128);
      k_gemm<128, 2, 64, 64><<<grid, 256, 0, stream>>>(p);
    }
  };
  auto stats = [&](const float* X, int si, int O, int rows) {
    float* st = STB + si * 1024;
    k_stats<<<256, 256, 0, stream>>>(X, st, O, rows);
    k_finstats<<<(O + 63) / 64, 64, 0, stream>>>(st, O, (float)rows);
  };
  auto norm = [&](const float* X, int si, int O, int G, int M, const float* Add,
                  u16* Yb, int ldyb, const long long* ybOff, float* Yf, int relu) {
    NormP p;
    p.X = X; p.st = STB + si * 1024; p.Add = Add; p.Yb = Yb; p.Yf = Yf;
    p.ldyb = ldyb; p.O = O; p.G = G; p.M = M; p.relu = relu;
    for (int g = 0; g < 8; g++) p.ybOff[g] = ybOff ? ybOff[(g < G) ? g : 0] : 0;
    long long total = (long long)G * M * (O / 4);
    k_norm<<<(int)((total + 255) / 256), 256, 0, stream>>>(p);
  };

  // cv1 -> bn relu -> cat[0:512]
  gemm(0, 0, 512, 512, 2304, 2, XBF, 2304LL * 512, 0, 512, YA, nullptr, nullptr);
  stats(YA, 0, 512, 4608);
  { long long yo[2] = {0, 2304LL * 1024};
    norm(YA, 0, 512, 2, 2304, nullptr, CATB, 1024, yo, nullptr, 1); }

  // qkv
  gemm(0, 262144, 768, 256, 2304, 2, CATB, 2304LL * 1024, 256, 1024, QKVF, nullptr, nullptr);
  // attention
  k_attn<<<1152, 256, 0, stream>>>(QKVF, AOB);
  // pe + residual
  k_pe<<<1152, 256, 0, stream>>>(CATB, WPE, RF);
  // aproj (+rf) -> a1 (f32 + bf16)
  gemm(0, 458752, 256, 256, 2304, 2, AOB, 2304LL * 256, 0, 256, A1F, RF, A1B);

  // ffn1 -> bn relu -> hb
  gemm(0, 524288, 512, 256, 2304, 2, A1B, 2304LL * 256, 0, 256, YA, nullptr, nullptr);
  stats(YA, 1, 512, 4608);
  { long long yo[2] = {0, 2304LL * 512};
    norm(YA, 1, 512, 2, 2304, nullptr, HB, 512, yo, nullptr, 1); }

  // ffn2 -> bn -> +a1 -> cat[512:768]
  gemm(0, 655360, 256, 512, 2304, 2, HB, 2304LL * 512, 0, 512, YA, nullptr, nullptr);
  stats(YA, 2, 256, 4608);
  { long long yo[2] = {512, 2304LL * 1024 + 512};
    norm(YA, 2, 256, 2, 2304, A1F, CATB, 1024, yo, nullptr, 0); }

  // ec -> bn relu -> ef (f32)
  gemm(0, 786432, 128, 256, 2304, 2, CATB, 2304LL * 1024, 512, 1024, YA, nullptr, nullptr);
  stats(YA, 3, 128, 4608);
  norm(YA, 3, 128, 2, 2304, nullptr, nullptr, 0, nullptr, EF, 1);

  // guide, gate, im2col
  k_guide<<<1, 256, 0, stream>>>(guide, glw, glb, GV);
  k_gate<<<8, 256, 0, stream>>>(EF, GV, GT);
  k_im2col<<<162, 256, 0, stream>>>(EF, GT, COLB);

  // mproj -> bn relu -> cat[768:1024]
  gemm(1, 819200, 256, 1152, 576, 8, COLB, 576LL * 1152, 0, 1152, YA, nullptr, nullptr);
  stats(YA, 4, 256, 4608);
  { long long yo[8];
    for (int g = 0; g < 8; g++)
      yo[g] = (long long)(g >> 2) * 2304 * 1024 + (long long)(g & 3) * 576 * 1024 + 768;
    norm(YA, 4, 256, 8, 576, nullptr, CATB, 1024, yo, nullptr, 1); }

  // cv2 -> bn relu -> out (transpose)
  gemm(0, 1114112, 512, 1024, 2304, 2, CATB, 2304LL * 1024, 0, 1024, YA, nullptr, nullptr);
  stats(YA, 5, 512, 4608);
  k_normT<<<2304, 256, 0, stream>>>(YA, STB + 5 * 1024, out);
}

// Round 3
// 390.009 us; speedup vs baseline: 2.1841x; 1.2038x over previous
//
#include <hip/hip_runtime.h>
#include <math.h>

typedef __bf16 bf16x8 __attribute__((ext_vector_type(8)));
typedef float f32x4 __attribute__((ext_vector_type(4)));
typedef unsigned short u16;
typedef unsigned int u32;

__device__ __forceinline__ u16 f2bf(float f) {
  u32 u = __float_as_uint(f);
  u32 r = u + 0x7FFF + ((u >> 16) & 1);
  return (u16)(r >> 16);
}
__device__ __forceinline__ float bf2f(u16 h) { return __uint_as_float(((u32)h) << 16); }

// ---------------- arena (byte offsets) ----------------
static constexpr size_t OB_WBF = 0;                       // 1,638,400 u16
static constexpr size_t OB_WPE = 3276800;                 // 2304 f32
static constexpr size_t OB_ST  = 3286016;                 // 6 x 4096B stats
static constexpr size_t OB_GV  = 3310592;                 // 256 f32
static constexpr size_t OB_GT  = 3311616;                 // 8 f32 gates
static constexpr size_t OB_GACC= 3311680;                 // 8 f32 gate accum
static constexpr size_t OB_CAT = 3311872;                 // bf16 [2][2304][1024]
static constexpr size_t OB_YA  = OB_CAT + 9437184;        // f32 gemm out (max 9.4MB)
static constexpr size_t OB_U1  = OB_YA + 9437184;         // xbf16 -> a1f f32 (4.7MB)
static constexpr size_t OB_U2  = OB_U1 + 4718592;         // qkv f32 (14.2MB) -> colb+ef
static constexpr size_t OB_U3  = OB_U2 + 14155776;        // rf f32 -> hb bf16 (4.7MB)
static constexpr size_t OB_AOB = OB_U3 + 4718592;         // attn out bf16 (2.36MB)
static constexpr size_t OB_A1B = OB_AOB + 2359296;        // a1 bf16 (2.36MB)
static constexpr size_t WS_TOTAL = OB_A1B + 2359296;      // ~50.5MB

// ---------------- weight prep: w = m*cos(p) -> bf16 (mproj tap-major remap) ----------------
struct WPrepP {
  const float* m[8]; const float* p[8];
  u16* out; const float* pem; const float* pep; float* peout;
  int cum[9];
};
__global__ __launch_bounds__(256) void k_wprep(WPrepP P) {
  int i = blockIdx.x * 256 + threadIdx.x;
  if (i < 2304) P.peout[i] = P.pem[i] * cosf(P.pep[i]);
  if (i >= P.cum[8]) return;
  int s = 0;
  while (s < 7 && i >= P.cum[s + 1]) s++;
  int j = i - P.cum[s];
  int src = j;
  if (s == 6) {  // mproj: out[o][kk*128+cc] <- in[(o*128+cc)*9+kk]
    int o = j / 1152, r = j % 1152, kk = r >> 7, cc = r & 127;
    src = (o * 128 + cc) * 9 + kk;
  }
  P.out[i] = f2bf(P.m[s][src] * cosf(P.p[s][src]));
}

// ---------------- x transpose: [b][c][q][hw] f32 -> [b][q*576+hw][c] bf16 ----------------
__global__ __launch_bounds__(256) void k_xpose(const float* x, u16* xb) {
  int bid = blockIdx.x;
  int mt = bid % 18; bid /= 18;
  int ct = bid % 16; bid /= 16;
  int q = bid & 3, b = bid >> 2;
  __shared__ float tile[32][33];
  int tj = threadIdx.x & 31, ti = threadIdx.x >> 5;
  const float* xp = x + (((size_t)(b * 512 + ct * 32) * 4 + q) * 576) + mt * 32;
#pragma unroll
  for (int ii = 0; ii < 4; ii++)
    tile[ti + ii * 8][tj] = xp[(size_t)(ti + ii * 8) * 4 * 576 + tj];
  __syncthreads();
  u16* yp = xb + ((size_t)b * 2304 + q * 576 + mt * 32) * 512 + ct * 32;
#pragma unroll
  for (int mm = 0; mm < 4; mm++)
    yp[(size_t)(mm * 8 + ti) * 512 + tj] = f2bf(tile[tj][mm * 8 + ti]);
}

// ---------------- MFMA GEMM: Y[g][m][o] = sum_k W[o][k] X[g][m][k] ----------------
struct GemmP {
  const u16* W; const u16* X; float* Y; const float* Add; u16* Yb;
  long long xOff[8];
  int lda, O, K, M, G;
};

template <int BM, int NWO, int WO, int WM>
__global__ __launch_bounds__(256) void k_gemm(GemmP P) {
  constexpr int FO = WO / 16, FM = WM / 16;
  __shared__ __align__(16) char lds[16384 + BM * 128];
  const int mt = P.M / BM;
  const int ot = P.O >> 7;
  int bid = blockIdx.x;
  const int g = bid / (mt * ot);
  const int rr = bid % (mt * ot);
  const int ob = (rr / mt) << 7;
  const int mb = (rr % mt) * BM;
  const int t = threadIdx.x, lane = t & 63, wave = t >> 6;
  const int wo = (wave % NWO) * WO, wm = (wave / NWO) * WM;
  const u16* Wp = P.W + (size_t)ob * P.K;
  const u16* Xp = P.X + P.xOff[g] + (size_t)mb * P.lda;

  f32x4 acc[FO][FM] = {};

  for (int k0 = 0; k0 < P.K; k0 += 64) {
#pragma unroll
    for (int i = 0; i < 4; i++) {  // A: 128 rows x 8 kg
      int c = t + i * 256;
      int row = c >> 3, kg = c & 7;
      *(uint4*)&lds[((row << 3) + (kg ^ (row & 7))) << 4] =
          *(const uint4*)(Wp + (size_t)row * P.K + k0 + kg * 8);
    }
#pragma unroll
    for (int i = 0; i < BM * 8 / 256; i++) {  // B: BM rows x 8 kg
      int c = t + i * 256;
      int row = c >> 3, kg = c & 7;
      *(uint4*)&lds[16384 + (((row << 3) + (kg ^ (row & 7))) << 4)] =
          *(const uint4*)(Xp + (size_t)row * P.lda + k0 + kg * 8);
    }
    __syncthreads();
#pragma unroll
    for (int kk = 0; kk < 2; kk++) {
      int kgl = kk * 4 + (lane >> 4);
      bf16x8 af[FO], bfm[FM];
#pragma unroll
      for (int fo = 0; fo < FO; fo++) {
        int row = wo + fo * 16 + (lane & 15);
        af[fo] = *(bf16x8*)&lds[((row << 3) + (kgl ^ (row & 7))) << 4];
      }
#pragma unroll
      for (int fm = 0; fm < FM; fm++) {
        int row = wm + fm * 16 + (lane & 15);
        bfm[fm] = *(bf16x8*)&lds[16384 + (((row << 3) + (kgl ^ (row & 7))) << 4)];
      }
#pragma unroll
      for (int fo = 0; fo < FO; fo++)
#pragma unroll
        for (int fm = 0; fm < FM; fm++)
          acc[fo][fm] = __builtin_amdgcn_mfma_f32_16x16x32_bf16(af[fo], bfm[fm], acc[fo][fm], 0, 0, 0);
    }
    __syncthreads();
  }

  size_t ybase = (size_t)g * P.M * P.O;
#pragma unroll
  for (int fo = 0; fo < FO; fo++) {
    int ow = ob + wo + fo * 16 + ((lane >> 4) << 2);
#pragma unroll
    for (int fm = 0; fm < FM; fm++) {
      int m = mb + wm + fm * 16 + (lane & 15);
      f32x4 v = acc[fo][fm];
      size_t off = ybase + (size_t)m * P.O + ow;
      if (P.Add) v += *(const f32x4*)&P.Add[off];
      *(f32x4*)&P.Y[off] = v;
      if (P.Yb) {
        ushort4 r;
        r.x = f2bf(v[0]); r.y = f2bf(v[1]); r.z = f2bf(v[2]); r.w = f2bf(v[3]);
        *(ushort4*)&P.Yb[off] = r;
      }
    }
  }
}

// ---------------- BN stats (atomic partials over rows of [rows][O]) ----------------
__global__ __launch_bounds__(256) void k_stats(const float* X, float* st, int O, int rows) {
  float s0 = 0, q0 = 0, s1 = 0, q1 = 0;
  int c0 = threadIdx.x, c1 = threadIdx.x + 256;
  bool h0 = c0 < O, h1 = c1 < O;
  for (int r = blockIdx.x; r < rows; r += gridDim.x) {
    const float* xp = X + (size_t)r * O;
    if (h0) { float v = xp[c0]; s0 += v; q0 += v * v; }
    if (h1) { float v = xp[c1]; s1 += v; q1 += v * v; }
  }
  if (h0) { atomicAdd(&st[2 * c0], s0); atomicAdd(&st[2 * c0 + 1], q0); }
  if (h1) { atomicAdd(&st[2 * c1], s1); atomicAdd(&st[2 * c1 + 1], q1); }
}
__global__ void k_finstats(float* st, int O, float n) {
  int c = blockIdx.x * 64 + threadIdx.x;
  if (c >= O) return;
  float mean = st[2 * c] / n;
  float var = st[2 * c + 1] / n - mean * mean;
  st[2 * c] = mean;
  st[2 * c + 1] = rsqrtf(var + 1e-5f);
}

// ---------------- BN normalize (+add, relu) -> bf16 and/or f32 ----------------
struct NormP {
  const float* X; const float* st; const float* Add;
  u16* Yb; float* Yf;
  long long ybOff[8];
  int ldyb, O, G, M, relu;
};
__global__ __launch_bounds__(256) void k_norm(NormP P) {
  int O4 = P.O >> 2;
  long long idx = (long long)blockIdx.x * 256 + threadIdx.x;
  if (idx >= (long long)P.G * P.M * O4) return;
  int c4 = (int)(idx % O4);
  long long gm = idx / O4;
  int m = (int)(gm % P.M);
  int g = (int)(gm / P.M);
  size_t off = (size_t)gm * P.O + c4 * 4;
  f32x4 v = *(const f32x4*)&P.X[off];
#pragma unroll
  for (int j = 0; j < 4; j++) {
    int c = c4 * 4 + j;
    v[j] = (v[j] - P.st[2 * c]) * P.st[2 * c + 1];
  }
  if (P.Add) v += *(const f32x4*)&P.Add[off];
  if (P.relu) {
#pragma unroll
    for (int j = 0; j < 4; j++) v[j] = fmaxf(v[j], 0.f);
  }
  if (P.Yb) {
    ushort4 r;
    r.x = f2bf(v[0]); r.y = f2bf(v[1]); r.z = f2bf(v[2]); r.w = f2bf(v[3]);
    *(ushort4*)(P.Yb + P.ybOff[g] + (size_t)m * P.ldyb + c4 * 4) = r;
  }
  if (P.Yf) *(f32x4*)&P.Yf[off] = v;
}

// ---------------- final norm with transpose to [b][o][q][hw] f32 ----------------
__global__ __launch_bounds__(256) void k_normT(const float* X, const float* st, float* out) {
  int idx = blockIdx.x * 256 + threadIdx.x;  // (b*512+o)*576 + m4
  if (idx >= 2 * 512 * 576) return;
  int m4 = idx % 576;
  int bo = idx / 576;
  int o = bo & 511, b = bo >> 9;
  float mean = st[2 * o], rs = st[2 * o + 1];
  f32x4 v;
#pragma unroll
  for (int j = 0; j < 4; j++) {
    float x = X[((size_t)b * 2304 + m4 * 4 + j) * 512 + o];
    v[j] = fmaxf((x - mean) * rs, 0.f);
  }
  *(f32x4*)&out[(size_t)bo * 2304 + m4 * 4] = v;
}

// ---------------- depthwise 3x3 pe + residual: rf[g][m][c] = dw(b)+b ----------------
__global__ __launch_bounds__(256) void k_pe(const u16* catb, const float* wpe, float* rf) {
  int idx = blockIdx.x * 256 + threadIdx.x;  // (g*2304+m)*64 + c4
  if (idx >= 2 * 2304 * 64) return;
  int c4 = idx & 63;
  int gm = idx >> 6;
  int m = gm % 2304, g = gm / 2304;
  int q = m / 576, hw = m % 576, h = hw / 24, w = hw % 24;
  const u16* base = catb + (size_t)g * 2304 * 1024 + 256 + c4 * 4;
  float acc[4];
  {
    ushort4 cv = *(const ushort4*)(base + (size_t)m * 1024);
    acc[0] = bf2f(cv.x); acc[1] = bf2f(cv.y); acc[2] = bf2f(cv.z); acc[3] = bf2f(cv.w);
  }
#pragma unroll
  for (int kh = 0; kh < 3; kh++) {
    int hh = h + kh - 1;
    if (hh < 0 || hh > 23) continue;
#pragma unroll
    for (int kw = 0; kw < 3; kw++) {
      int ww = w + kw - 1;
      if (ww < 0 || ww > 23) continue;
      ushort4 cv = *(const ushort4*)(base + (size_t)(q * 576 + hh * 24 + ww) * 1024);
      float tap[4] = {bf2f(cv.x), bf2f(cv.y), bf2f(cv.z), bf2f(cv.w)};
#pragma unroll
      for (int j = 0; j < 4; j++)
        acc[j] = fmaf(wpe[(c4 * 4 + j) * 9 + kh * 3 + kw], tap[j], acc[j]);
    }
  }
  f32x4 v = {acc[0], acc[1], acc[2], acc[3]};
  *(f32x4*)&rf[(size_t)gm * 256 + c4 * 4] = v;
}

// ---------------- attention: no-max softmax (scores tiny), 4-way key split ----------------
#define KT 48
__global__ __launch_bounds__(256) void k_attn(const float* qkv, u16* ao) {
  int bid = blockIdx.x;
  int qt = bid % 9; bid /= 9;
  int qd = bid & 3; bid >>= 2;
  int head = bid & 15, b = bid >> 4;
  int lane = threadIdx.x & 63, wv = threadIdx.x >> 6;
  int n = qt * 64 + lane;
  const float* Qb = qkv + ((size_t)b * 2304 + qd * 576) * 768;

  float qv[16];
  {
    const float* qp = Qb + (size_t)n * 768 + head * 16;
#pragma unroll
    for (int c = 0; c < 16; c++) qv[c] = qp[c] * 0.25f;
  }

  __shared__ __align__(16) char shm[24576];
  float(*sK)[KT][16] = (float(*)[KT][16])shm;
  float(*sV)[KT][16] = (float(*)[KT][16])(shm + 12288);

  float sum = 0.f;
  float o[16];
#pragma unroll
  for (int d = 0; d < 16; d++) o[d] = 0.f;

  int k0w = wv * 144;
  for (int tile = 0; tile < 3; tile++) {
    int k0 = k0w + tile * KT;
    __syncthreads();
#pragma unroll
    for (int i = 0; i < 3; i++) {
      int cc = lane + i * 64;
      int mm = cc >> 2, c4 = cc & 3;
      const float* kp = Qb + (size_t)(k0 + mm) * 768 + 256 + head * 16 + c4 * 4;
      *(f32x4*)&sK[wv][mm][c4 * 4] = *(const f32x4*)kp;
      *(f32x4*)&sV[wv][mm][c4 * 4] = *(const f32x4*)(kp + 256);
    }
    __syncthreads();
    for (int mm = 0; mm < KT; mm++) {
      const float* kr = &sK[wv][mm][0];
      float s = 0.f;
#pragma unroll
      for (int c = 0; c < 16; c++) s = fmaf(qv[c], kr[c], s);
      float pv = __expf(s);
      sum += pv;
      const float* vr = &sV[wv][mm][0];
#pragma unroll
      for (int d = 0; d < 16; d++) o[d] = fmaf(pv, vr[d], o[d]);
    }
  }
  __syncthreads();
  float(*ps)[64] = (float(*)[64])shm;
  float(*po)[64][17] = (float(*)[64][17])(shm + 1024);
  ps[wv][lane] = sum;
#pragma unroll
  for (int d = 0; d < 16; d++) po[wv][lane][d] = o[d];
  __syncthreads();
  if (threadIdx.x < 64) {
    float S = 0.f;
    float oo[16];
#pragma unroll
    for (int d = 0; d < 16; d++) oo[d] = 0.f;
#pragma unroll
    for (int w = 0; w < 4; w++) {
      S += ps[w][lane];
#pragma unroll
      for (int d = 0; d < 16; d++) oo[d] += po[w][lane][d];
    }
    float inv = 1.f / S;
    u16* op = ao + ((size_t)b * 2304 + qd * 576 + n) * 256 + head * 16;
#pragma unroll
    for (int d4 = 0; d4 < 4; d4++) {
      ushort4 r;
      r.x = f2bf(oo[d4 * 4 + 0] * inv);
      r.y = f2bf(oo[d4 * 4 + 1] * inv);
      r.z = f2bf(oo[d4 * 4 + 2] * inv);
      r.w = f2bf(oo[d4 * 4 + 3] * inv);
      *(ushort4*)(op + d4 * 4) = r;
    }
  }
}

// ---------------- guide linear: one block per (b,e), 64-lane dot ----------------
__global__ __launch_bounds__(64) void k_guide(const float* guide, const float* glw,
                                              const float* glb, float* g) {
  int be = blockIdx.x;  // b*128+e
  int b = be >> 7, e = be & 127;
  const float* gr = guide + b * 512;
  const float* wr = glw + e * 512;
  float s = 0.f;
  for (int c = threadIdx.x; c < 512; c += 64) s = fmaf(gr[c], wr[c], s);
#pragma unroll
  for (int off = 32; off > 0; off >>= 1) s += __shfl_down(s, off, 64);
  if (threadIdx.x == 0) g[be] = s + glb[e];
}

// ---------------- gate partial: 144 blocks (8 bq x 18 chunks), atomicAdd ----------------
__global__ __launch_bounds__(256) void k_gatepart(const float* ef, const float* g, float* acc) {
  int bid = blockIdx.x;
  int chunk = bid % 18, bq = bid / 18;
  int b = bq >> 2, q = bq & 3;
  int c = threadIdx.x & 127, half = threadIdx.x >> 7;
  float gc = g[b * 128 + c];
  float s = 0.f;
  int r0 = chunk * 32;
  const float* base = ef + ((size_t)b * 2304 + q * 576 + r0) * 128 + c;
  for (int r = half; r < 32; r += 2) s = fmaf(base[(size_t)r * 128], gc, s);
#pragma unroll
  for (int off = 32; off > 0; off >>= 1) s += __shfl_down(s, off, 64);
  __shared__ float t1[4];
  int lane = threadIdx.x & 63, wv = threadIdx.x >> 6;
  if (lane == 0) t1[wv] = s;
  __syncthreads();
  if (threadIdx.x == 0) atomicAdd(&acc[bq], t1[0] + t1[1] + t1[2] + t1[3]);
}
__global__ void k_gatefin(const float* acc, float* gates) {
  int i = threadIdx.x;
  if (i >= 8) return;
  float a = acc[i] / sqrtf(73728.0f);
  gates[i] = 1.f / (1.f + expf(-a));
}

// ---------------- im2col (gated, tap-major k) -> bf16 col [g][n][kk*128+c] ----------------
__global__ __launch_bounds__(256) void k_im2col(const float* ef, const float* gates, u16* col) {
  int idx = blockIdx.x * 256 + threadIdx.x;  // (g*576+n)*9+kk
  if (idx >= 8 * 576 * 9) return;
  int kk = idx % 9;
  int gn = idx / 9;
  int n = gn % 576, g = gn / 576;
  int b = g >> 2, q = g & 3;
  int h = n / 24 + kk / 3 - 1, w = n % 24 + kk % 3 - 1;
  u16* cp = col + (size_t)gn * 1152 + kk * 128;
  if (h < 0 || h > 23 || w < 0 || w > 23) {
    ushort4 z = {0, 0, 0, 0};
#pragma unroll
    for (int c4 = 0; c4 < 32; c4++) *(ushort4*)&cp[c4 * 4] = z;
    return;
  }
  float gt = gates[g];
  const float* ep = ef + ((size_t)b * 2304 + q * 576 + h * 24 + w) * 128;
  for (int c4 = 0; c4 < 32; c4++) {
    f32x4 v = *(const f32x4*)&ep[c4 * 4];
    ushort4 r;
    r.x = f2bf(v[0] * gt); r.y = f2bf(v[1] * gt);
    r.z = f2bf(v[2] * gt); r.w = f2bf(v[3] * gt);
    *(ushort4*)&cp[c4 * 4] = r;
  }
}

// ---------------- host ----------------
extern "C" void kernel_launch(void* const* d_in, const int* in_sizes, int n_in,
                              void* d_out, int out_size, void* d_ws, size_t ws_size,
                              hipStream_t stream) {
  if (ws_size < WS_TOTAL) return;
  char* ws = (char*)d_ws;
  u16* WB = (u16*)(ws + OB_WBF);
  float* WPE = (float*)(ws + OB_WPE);
  float* STB = (float*)(ws + OB_ST);
  float* GV = (float*)(ws + OB_GV);
  float* GT = (float*)(ws + OB_GT);
  float* GACC = (float*)(ws + OB_GACC);
  u16* CATB = (u16*)(ws + OB_CAT);
  float* YA = (float*)(ws + OB_YA);
  u16* XBF = (u16*)(ws + OB_U1);
  float* A1F = (float*)(ws + OB_U1);
  float* QKVF = (float*)(ws + OB_U2);
  u16* COLB = (u16*)(ws + OB_U2);
  float* EF = (float*)(ws + OB_U2 + 10616832);
  float* RF = (float*)(ws + OB_U3);
  u16* HB = (u16*)(ws + OB_U3);
  u16* AOB = (u16*)(ws + OB_AOB);
  u16* A1B = (u16*)(ws + OB_A1B);
  float* out = (float*)d_out;
  const float* x = (const float*)d_in[0];
  const float* guide = (const float*)d_in[1];
  const float* glw = (const float*)d_in[16];
  const float* glb = (const float*)d_in[17];

  // zero stats (24576B) + GV + GT + GACC region
  hipMemsetAsync(ws + OB_ST, 0, 25856, stream);

  {  // weights
    WPrepP p;
    const int mi[8] = {2, 4, 6, 10, 12, 14, 18, 20};
    const int sz[8] = {262144, 196608, 65536, 131072, 131072, 32768, 294912, 524288};
    int c = 0;
    for (int i = 0; i < 8; i++) {
      p.m[i] = (const float*)d_in[mi[i]];
      p.p[i] = (const float*)d_in[mi[i] + 1];
      p.cum[i] = c;
      c += sz[i];
    }
    p.cum[8] = c;
    p.out = WB;
    p.pem = (const float*)d_in[8];
    p.pep = (const float*)d_in[9];
    p.peout = WPE;
    k_wprep<<<(c + 255) / 256, 256, 0, stream>>>(p);
  }
  k_xpose<<<2304, 256, 0, stream>>>(x, XBF);

  auto gemm = [&](int bm64, size_t wOff, int O, int K, int M, int G,
                  const u16* X, long long xs, long long xadd, int lda,
                  float* Y, const float* Add, u16* Yb) {
    GemmP p;
    p.W = WB + wOff; p.X = X; p.Y = Y; p.Add = Add; p.Yb = Yb;
    p.lda = lda; p.O = O; p.K = K; p.M = M; p.G = G;
    for (int g = 0; g < 8; g++) p.xOff[g] = (long long)(g < G ? g : 0) * xs + xadd;
    if (bm64) {
      int grid = G * (O / 128) * (M / 64);
      k_gemm<64, 4, 32, 64><<<grid, 256, 0, stream>>>(p);
    } else {
      int grid = G * (O / 128) * (M / 128);
      k_gemm<128, 2, 64, 64><<<grid, 256, 0, stream>>>(p);
    }
  };
  auto stats = [&](const float* X, int si, int O, int rows) {
    float* st = STB + si * 1024;
    k_stats<<<256, 256, 0, stream>>>(X, st, O, rows);
    k_finstats<<<(O + 63) / 64, 64, 0, stream>>>(st, O, (float)rows);
  };
  auto norm = [&](const float* X, int si, int O, int G, int M, const float* Add,
                  u16* Yb, int ldyb, const long long* ybOff, float* Yf, int relu) {
    NormP p;
    p.X = X; p.st = STB + si * 1024; p.Add = Add; p.Yb = Yb; p.Yf = Yf;
    p.ldyb = ldyb; p.O = O; p.G = G; p.M = M; p.relu = relu;
    for (int g = 0; g < 8; g++) p.ybOff[g] = ybOff ? ybOff[(g < G) ? g : 0] : 0;
    long long total = (long long)G * M * (O / 4);
    k_norm<<<(int)((total + 255) / 256), 256, 0, stream>>>(p);
  };

  // cv1 -> bn relu -> cat[0:512]
  gemm(0, 0, 512, 512, 2304, 2, XBF, 2304LL * 512, 0, 512, YA, nullptr, nullptr);
  stats(YA, 0, 512, 4608);
  { long long yo[2] = {0, 2304LL * 1024};
    norm(YA, 0, 512, 2, 2304, nullptr, CATB, 1024, yo, nullptr, 1); }

  // qkv
  gemm(0, 262144, 768, 256, 2304, 2, CATB, 2304LL * 1024, 256, 1024, QKVF, nullptr, nullptr);
  // attention
  k_attn<<<1152, 256, 0, stream>>>(QKVF, AOB);
  // pe + residual
  k_pe<<<1152, 256, 0, stream>>>(CATB, WPE, RF);
  // aproj (+rf) -> a1 (f32 + bf16)
  gemm(0, 458752, 256, 256, 2304, 2, AOB, 2304LL * 256, 0, 256, A1F, RF, A1B);

  // ffn1 -> bn relu -> hb
  gemm(0, 524288, 512, 256, 2304, 2, A1B, 2304LL * 256, 0, 256, YA, nullptr, nullptr);
  stats(YA, 1, 512, 4608);
  { long long yo[2] = {0, 2304LL * 512};
    norm(YA, 1, 512, 2, 2304, nullptr, HB, 512, yo, nullptr, 1); }

  // ffn2 -> bn -> +a1 -> cat[512:768]
  gemm(0, 655360, 256, 512, 2304, 2, HB, 2304LL * 512, 0, 512, YA, nullptr, nullptr);
  stats(YA, 2, 256, 4608);
  { long long yo[2] = {512, 2304LL * 1024 + 512};
    norm(YA, 2, 256, 2, 2304, A1F, CATB, 1024, yo, nullptr, 0); }

  // ec -> bn relu -> ef (f32)
  gemm(0, 786432, 128, 256, 2304, 2, CATB, 2304LL * 1024, 512, 1024, YA, nullptr, nullptr);
  stats(YA, 3, 128, 4608);
  norm(YA, 3, 128, 2, 2304, nullptr, nullptr, 0, nullptr, EF, 1);

  // guide, gate (parallel partial + finish), im2col
  k_guide<<<256, 64, 0, stream>>>(guide, glw, glb, GV);
  k_gatepart<<<144, 256, 0, stream>>>(EF, GV, GACC);
  k_gatefin<<<1, 64, 0, stream>>>(GACC, GT);
  k_im2col<<<162, 256, 0, stream>>>(EF, GT, COLB);

  // mproj -> bn relu -> cat[768:1024]
  gemm(1, 819200, 256, 1152, 576, 8, COLB, 576LL * 1152, 0, 1152, YA, nullptr, nullptr);
  stats(YA, 4, 256, 4608);
  { long long yo[8];
    for (int g = 0; g < 8; g++)
      yo[g] = (long long)(g >> 2) * 2304 * 1024 + (long long)(g & 3) * 576 * 1024 + 768;
    norm(YA, 4, 256, 8, 576, nullptr, CATB, 1024, yo, nullptr, 1); }

  // cv2 -> bn relu -> out (transpose)
  gemm(0, 1114112, 512, 1024, 2304, 2, CATB, 2304LL * 1024, 0, 1024, YA, nullptr, nullptr);
  stats(YA, 5, 512, 4608);
  k_normT<<<2304, 256, 0, stream>>>(YA, STB + 5 * 1024, out);
}

// Round 4
// 362.544 us; speedup vs baseline: 2.3496x; 1.0758x over previous
//
#include <hip/hip_runtime.h>
#include <math.h>

typedef __bf16 bf16x8 __attribute__((ext_vector_type(8)));
typedef float f32x4 __attribute__((ext_vector_type(4)));
typedef unsigned short u16;
typedef unsigned int u32;

__device__ __forceinline__ u16 f2bf(float f) {
  u32 u = __float_as_uint(f);
  u32 r = u + 0x7FFF + ((u >> 16) & 1);
  return (u16)(r >> 16);
}
__device__ __forceinline__ float bf2f(u16 h) { return __uint_as_float(((u32)h) << 16); }

// ---------------- arena (byte offsets) ----------------
static constexpr size_t OB_WBF = 0;                       // 1,638,400 u16
static constexpr size_t OB_WPE = 3276800;                 // 2304 f32
static constexpr size_t OB_ST  = 3286016;                 // 6 x 4096B stats
static constexpr size_t OB_GV  = 3310592;                 // 256 f32
static constexpr size_t OB_GT  = 3311616;                 // 8 f32 gates
static constexpr size_t OB_GACC= 3311680;                 // 8 f32 gate accum
static constexpr size_t OB_CAT = 3311872;                 // bf16 [2][2304][1024]
static constexpr size_t OB_YA  = OB_CAT + 9437184;        // f32 gemm out (max 9.4MB)
static constexpr size_t OB_U1  = OB_YA + 9437184;         // xbf16 -> a1f f32 (4.7MB)
static constexpr size_t OB_U2  = OB_U1 + 4718592;         // qkv bf16 (7.1MB) -> colb ; +ef f32
static constexpr size_t OB_U3  = OB_U2 + 14155776;        // rf f32 -> hb bf16 (4.7MB)
static constexpr size_t OB_AOB = OB_U3 + 4718592;         // attn out bf16 (2.36MB)
static constexpr size_t OB_A1B = OB_AOB + 2359296;        // a1 bf16 (2.36MB)
static constexpr size_t WS_TOTAL = OB_A1B + 2359296;      // ~50.5MB

// ---------------- weight prep: w = m*cos(p) -> bf16 (mproj tap-major remap) ----------------
struct WPrepP {
  const float* m[8]; const float* p[8];
  u16* out; const float* pem; const float* pep; float* peout;
  int cum[9];
};
__global__ __launch_bounds__(256) void k_wprep(WPrepP P) {
  int i = blockIdx.x * 256 + threadIdx.x;
  if (i < 2304) P.peout[i] = P.pem[i] * cosf(P.pep[i]);
  if (i >= P.cum[8]) return;
  int s = 0;
  while (s < 7 && i >= P.cum[s + 1]) s++;
  int j = i - P.cum[s];
  int src = j;
  if (s == 6) {  // mproj: out[o][kk*128+cc] <- in[(o*128+cc)*9+kk]
    int o = j / 1152, r = j % 1152, kk = r >> 7, cc = r & 127;
    src = (o * 128 + cc) * 9 + kk;
  }
  P.out[i] = f2bf(P.m[s][src] * cosf(P.p[s][src]));
}

// ---------------- x transpose: [b][c][q][hw] f32 -> [b][q*576+hw][c] bf16 ----------------
__global__ __launch_bounds__(256) void k_xpose(const float* x, u16* xb) {
  int bid = blockIdx.x;
  int mt = bid % 18; bid /= 18;
  int ct = bid % 16; bid /= 16;
  int q = bid & 3, b = bid >> 2;
  __shared__ float tile[32][33];
  int tj = threadIdx.x & 31, ti = threadIdx.x >> 5;
  const float* xp = x + (((size_t)(b * 512 + ct * 32) * 4 + q) * 576) + mt * 32;
#pragma unroll
  for (int ii = 0; ii < 4; ii++)
    tile[ti + ii * 8][tj] = xp[(size_t)(ti + ii * 8) * 4 * 576 + tj];
  __syncthreads();
  u16* yp = xb + ((size_t)b * 2304 + q * 576 + mt * 32) * 512 + ct * 32;
#pragma unroll
  for (int mm = 0; mm < 4; mm++)
    yp[(size_t)(mm * 8 + ti) * 512 + tj] = f2bf(tile[tj][mm * 8 + ti]);
}

// ---------------- MFMA GEMM: Y[g][m][o] = sum_k W[o][k] X[g][m][k] ----------------
struct GemmP {
  const u16* W; const u16* X; float* Y; const float* Add; u16* Yb;
  long long xOff[8];
  int lda, O, K, M, G;
};

template <int BM, int NWO, int WO, int WM>
__global__ __launch_bounds__(256) void k_gemm(GemmP P) {
  constexpr int FO = WO / 16, FM = WM / 16;
  __shared__ __align__(16) char lds[16384 + BM * 128];
  const int mt = P.M / BM;
  const int ot = P.O >> 7;
  int bid = blockIdx.x;
  const int g = bid / (mt * ot);
  const int rr = bid % (mt * ot);
  const int ob = (rr / mt) << 7;
  const int mb = (rr % mt) * BM;
  const int t = threadIdx.x, lane = t & 63, wave = t >> 6;
  const int wo = (wave % NWO) * WO, wm = (wave / NWO) * WM;
  const u16* Wp = P.W + (size_t)ob * P.K;
  const u16* Xp = P.X + P.xOff[g] + (size_t)mb * P.lda;

  f32x4 acc[FO][FM] = {};

  for (int k0 = 0; k0 < P.K; k0 += 64) {
#pragma unroll
    for (int i = 0; i < 4; i++) {  // A: 128 rows x 8 kg
      int c = t + i * 256;
      int row = c >> 3, kg = c & 7;
      *(uint4*)&lds[((row << 3) + (kg ^ (row & 7))) << 4] =
          *(const uint4*)(Wp + (size_t)row * P.K + k0 + kg * 8);
    }
#pragma unroll
    for (int i = 0; i < BM * 8 / 256; i++) {  // B: BM rows x 8 kg
      int c = t + i * 256;
      int row = c >> 3, kg = c & 7;
      *(uint4*)&lds[16384 + (((row << 3) + (kg ^ (row & 7))) << 4)] =
          *(const uint4*)(Xp + (size_t)row * P.lda + k0 + kg * 8);
    }
    __syncthreads();
#pragma unroll
    for (int kk = 0; kk < 2; kk++) {
      int kgl = kk * 4 + (lane >> 4);
      bf16x8 af[FO], bfm[FM];
#pragma unroll
      for (int fo = 0; fo < FO; fo++) {
        int row = wo + fo * 16 + (lane & 15);
        af[fo] = *(bf16x8*)&lds[((row << 3) + (kgl ^ (row & 7))) << 4];
      }
#pragma unroll
      for (int fm = 0; fm < FM; fm++) {
        int row = wm + fm * 16 + (lane & 15);
        bfm[fm] = *(bf16x8*)&lds[16384 + (((row << 3) + (kgl ^ (row & 7))) << 4)];
      }
#pragma unroll
      for (int fo = 0; fo < FO; fo++)
#pragma unroll
        for (int fm = 0; fm < FM; fm++)
          acc[fo][fm] = __builtin_amdgcn_mfma_f32_16x16x32_bf16(af[fo], bfm[fm], acc[fo][fm], 0, 0, 0);
    }
    __syncthreads();
  }

  size_t ybase = (size_t)g * P.M * P.O;
#pragma unroll
  for (int fo = 0; fo < FO; fo++) {
    int ow = ob + wo + fo * 16 + ((lane >> 4) << 2);
#pragma unroll
    for (int fm = 0; fm < FM; fm++) {
      int m = mb + wm + fm * 16 + (lane & 15);
      f32x4 v = acc[fo][fm];
      size_t off = ybase + (size_t)m * P.O + ow;
      if (P.Add) v += *(const f32x4*)&P.Add[off];
      if (P.Y) *(f32x4*)&P.Y[off] = v;
      if (P.Yb) {
        ushort4 r;
        r.x = f2bf(v[0]); r.y = f2bf(v[1]); r.z = f2bf(v[2]); r.w = f2bf(v[3]);
        *(ushort4*)&P.Yb[off] = r;
      }
    }
  }
}

// ---------------- BN stats (atomic partials over rows of [rows][O]) ----------------
__global__ __launch_bounds__(256) void k_stats(const float* X, float* st, int O, int rows) {
  float s0 = 0, q0 = 0, s1 = 0, q1 = 0;
  int c0 = threadIdx.x, c1 = threadIdx.x + 256;
  bool h0 = c0 < O, h1 = c1 < O;
  for (int r = blockIdx.x; r < rows; r += gridDim.x) {
    const float* xp = X + (size_t)r * O;
    if (h0) { float v = xp[c0]; s0 += v; q0 += v * v; }
    if (h1) { float v = xp[c1]; s1 += v; q1 += v * v; }
  }
  if (h0) { atomicAdd(&st[2 * c0], s0); atomicAdd(&st[2 * c0 + 1], q0); }
  if (h1) { atomicAdd(&st[2 * c1], s1); atomicAdd(&st[2 * c1 + 1], q1); }
}
__global__ void k_finstats(float* st, int O, float n) {
  int c = blockIdx.x * 64 + threadIdx.x;
  if (c >= O) return;
  float mean = st[2 * c] / n;
  float var = st[2 * c + 1] / n - mean * mean;
  st[2 * c] = mean;
  st[2 * c + 1] = rsqrtf(var + 1e-5f);
}

// ---------------- BN normalize (+add, relu) -> bf16 and/or f32 ----------------
struct NormP {
  const float* X; const float* st; const float* Add;
  u16* Yb; float* Yf;
  long long ybOff[8];
  int ldyb, O, G, M, relu;
};
__global__ __launch_bounds__(256) void k_norm(NormP P) {
  int O4 = P.O >> 2;
  long long idx = (long long)blockIdx.x * 256 + threadIdx.x;
  if (idx >= (long long)P.G * P.M * O4) return;
  int c4 = (int)(idx % O4);
  long long gm = idx / O4;
  int m = (int)(gm % P.M);
  int g = (int)(gm / P.M);
  size_t off = (size_t)gm * P.O + c4 * 4;
  f32x4 v = *(const f32x4*)&P.X[off];
#pragma unroll
  for (int j = 0; j < 4; j++) {
    int c = c4 * 4 + j;
    v[j] = (v[j] - P.st[2 * c]) * P.st[2 * c + 1];
  }
  if (P.Add) v += *(const f32x4*)&P.Add[off];
  if (P.relu) {
#pragma unroll
    for (int j = 0; j < 4; j++) v[j] = fmaxf(v[j], 0.f);
  }
  if (P.Yb) {
    ushort4 r;
    r.x = f2bf(v[0]); r.y = f2bf(v[1]); r.z = f2bf(v[2]); r.w = f2bf(v[3]);
    *(ushort4*)(P.Yb + P.ybOff[g] + (size_t)m * P.ldyb + c4 * 4) = r;
  }
  if (P.Yf) *(f32x4*)&P.Yf[off] = v;
}

// ---------------- final norm with transpose to [b][o][q][hw] f32 ----------------
__global__ __launch_bounds__(256) void k_normT(const float* X, const float* st, float* out) {
  int idx = blockIdx.x * 256 + threadIdx.x;  // (b*512+o)*576 + m4
  if (idx >= 2 * 512 * 576) return;
  int m4 = idx % 576;
  int bo = idx / 576;
  int o = bo & 511, b = bo >> 9;
  float mean = st[2 * o], rs = st[2 * o + 1];
  f32x4 v;
#pragma unroll
  for (int j = 0; j < 4; j++) {
    float x = X[((size_t)b * 2304 + m4 * 4 + j) * 512 + o];
    v[j] = fmaxf((x - mean) * rs, 0.f);
  }
  *(f32x4*)&out[(size_t)bo * 2304 + m4 * 4] = v;
}

// ---------------- depthwise 3x3 pe + residual: rf[g][m][c] = dw(b)+b ----------------
__global__ __launch_bounds__(256) void k_pe(const u16* catb, const float* wpe, float* rf) {
  int idx = blockIdx.x * 256 + threadIdx.x;  // (g*2304+m)*64 + c4
  if (idx >= 2 * 2304 * 64) return;
  int c4 = idx & 63;
  int gm = idx >> 6;
  int m = gm % 2304, g = gm / 2304;
  int q = m / 576, hw = m % 576, h = hw / 24, w = hw % 24;
  const u16* base = catb + (size_t)g * 2304 * 1024 + 256 + c4 * 4;
  float acc[4];
  {
    ushort4 cv = *(const ushort4*)(base + (size_t)m * 1024);
    acc[0] = bf2f(cv.x); acc[1] = bf2f(cv.y); acc[2] = bf2f(cv.z); acc[3] = bf2f(cv.w);
  }
#pragma unroll
  for (int kh = 0; kh < 3; kh++) {
    int hh = h + kh - 1;
    if (hh < 0 || hh > 23) continue;
#pragma unroll
    for (int kw = 0; kw < 3; kw++) {
      int ww = w + kw - 1;
      if (ww < 0 || ww > 23) continue;
      ushort4 cv = *(const ushort4*)(base + (size_t)(q * 576 + hh * 24 + ww) * 1024);
      float tap[4] = {bf2f(cv.x), bf2f(cv.y), bf2f(cv.z), bf2f(cv.w)};
#pragma unroll
      for (int j = 0; j < 4; j++)
        acc[j] = fmaf(wpe[(c4 * 4 + j) * 9 + kh * 3 + kw], tap[j], acc[j]);
    }
  }
  f32x4 v = {acc[0], acc[1], acc[2], acc[3]};
  *(f32x4*)&rf[(size_t)gm * 256 + c4 * 4] = v;
}

// ---------------- MFMA flash attention (no-max softmax; scores tiny) ----------------
// block = (b, head, qd, qthird). LDS: K[576][24] scaled bf16 (27648B),
// VT[72][16][8] bf16 (18432B), P per-wave [4][16][8] bf16 (4x1024B). Total 50176B.
__global__ __launch_bounds__(256) void k_attn(const u16* qkv, u16* ao) {
  int bid = blockIdx.x;
  int tq = bid % 3; int u = bid / 3;
  int qd = u & 3; u >>= 2;
  int head = u & 15, b = u >> 4;
  int t = threadIdx.x, lane = t & 63, wv = t >> 6;
  int g = lane >> 4, q = lane & 15;
  size_t tok0 = (size_t)b * 2304 + qd * 576;
  const u16* QKV = qkv + tok0 * 768;

  __shared__ __align__(16) char shm[50176];
  u16* Kl = (u16*)(shm);                       // [576][24] (pad 48B stride)
  u16* VT = (u16*)(shm + 27648);               // [(m>>3)][d][m&7]
  u16* Pl = (u16*)(shm + 46080 + wv * 1024);   // [4][16][8]

  // stage K, prescaled by 0.25 (exact in bf16)
  for (int i = t; i < 1152; i += 256) {
    int m = i >> 1, half = i & 1;
    const u16* src = QKV + (size_t)m * 768 + 256 + head * 16 + half * 8;
    u16 tmp[8];
    *(uint4*)tmp = *(const uint4*)src;
    ushort4 lo, hi;
    lo.x = f2bf(bf2f(tmp[0]) * 0.25f); lo.y = f2bf(bf2f(tmp[1]) * 0.25f);
    lo.z = f2bf(bf2f(tmp[2]) * 0.25f); lo.w = f2bf(bf2f(tmp[3]) * 0.25f);
    hi.x = f2bf(bf2f(tmp[4]) * 0.25f); hi.y = f2bf(bf2f(tmp[5]) * 0.25f);
    hi.z = f2bf(bf2f(tmp[6]) * 0.25f); hi.w = f2bf(bf2f(tmp[7]) * 0.25f);
    u16* dst = Kl + m * 24 + half * 8;
    *(ushort4*)dst = lo;
    *(ushort4*)(dst + 4) = hi;
  }
  // stage V transposed: VT[(m>>3)*128 + d*8 + (m&7)]
  for (int mm = t; mm < 576; mm += 256) {
    const u16* src = QKV + (size_t)mm * 768 + 512 + head * 16;
    u16 tmp[16];
    *(uint4*)tmp = *(const uint4*)src;
    *(uint4*)(tmp + 8) = *(const uint4*)(src + 8);
    u16* dst = VT + (mm >> 3) * 128 + (mm & 7);
#pragma unroll
    for (int d = 0; d < 16; d++) dst[d * 8] = tmp[d];
  }
  __syncthreads();

#pragma unroll 1
  for (int i = 0; i < 3; i++) {
    int tl = wv * 3 + i;
    int qbase = tq * 192 + tl * 16;
    // Q B-fragment: col=q, k=8g+j (k>=16 -> zero)
    bf16x8 qf = {};
    if (g < 2)
      qf = *(const bf16x8*)(QKV + (size_t)(qbase + q) * 768 + head * 16 + g * 8);

    f32x4 acc_o = {};
    float ssum = 0.f;

    for (int ch = 0; ch < 18; ch++) {
      int m0 = ch * 32;
      f32x4 s[2];
#pragma unroll
      for (int h = 0; h < 2; h++) {
        bf16x8 kf = {};
        if (g < 2)
          kf = *(const bf16x8*)(Kl + (size_t)(m0 + h * 16 + q) * 24 + g * 8);
        f32x4 z = {};
        s[h] = __builtin_amdgcn_mfma_f32_16x16x32_bf16(kf, qf, z, 0, 0, 0);
      }
#pragma unroll
      for (int h = 0; h < 2; h++) {
        float p0 = __expf(s[h][0]);
        float p1 = __expf(s[h][1]);
        float p2 = __expf(s[h][2]);
        float p3 = __expf(s[h][3]);
        ssum += (p0 + p1) + (p2 + p3);
        ushort4 w;
        w.x = f2bf(p0); w.y = f2bf(p1); w.z = f2bf(p2); w.w = f2bf(p3);
        // rows m_loc = h*16 + 4g + r  ->  Pl[h*2 + (g>>1)][q][(g&1)*4 + r]
        *(ushort4*)(Pl + ((h * 2 + (g >> 1)) * 16 + q) * 8 + (g & 1) * 4) = w;
      }
      // PV: A = VT (row=d=q-slot, k=m0+8g+j), B = P (col=q, k=8g+j)
      bf16x8 va = *(const bf16x8*)(VT + ((m0 >> 3) + g) * 128 + q * 8);
      bf16x8 pa = *(const bf16x8*)(Pl + (g * 16 + q) * 8);
      acc_o = __builtin_amdgcn_mfma_f32_16x16x32_bf16(va, pa, acc_o, 0, 0, 0);
    }

    ssum += __shfl_xor(ssum, 16, 64);
    ssum += __shfl_xor(ssum, 32, 64);
    float inv = 1.f / ssum;
    u16* op = ao + (tok0 + qbase + q) * 256 + head * 16 + g * 4;
    ushort4 r;
    r.x = f2bf(acc_o[0] * inv);
    r.y = f2bf(acc_o[1] * inv);
    r.z = f2bf(acc_o[2] * inv);
    r.w = f2bf(acc_o[3] * inv);
    *(ushort4*)op = r;
  }
}

// ---------------- guide linear: one block per (b,e), 64-lane dot ----------------
__global__ __launch_bounds__(64) void k_guide(const float* guide, const float* glw,
                                              const float* glb, float* g) {
  int be = blockIdx.x;  // b*128+e
  int b = be >> 7, e = be & 127;
  const float* gr = guide + b * 512;
  const float* wr = glw + e * 512;
  float s = 0.f;
  for (int c = threadIdx.x; c < 512; c += 64) s = fmaf(gr[c], wr[c], s);
#pragma unroll
  for (int off = 32; off > 0; off >>= 1) s += __shfl_down(s, off, 64);
  if (threadIdx.x == 0) g[be] = s + glb[e];
}

// ---------------- gate partial: 144 blocks (8 bq x 18 chunks), atomicAdd ----------------
__global__ __launch_bounds__(256) void k_gatepart(const float* ef, const float* g, float* acc) {
  int bid = blockIdx.x;
  int chunk = bid % 18, bq = bid / 18;
  int b = bq >> 2, q = bq & 3;
  int c = threadIdx.x & 127, half = threadIdx.x >> 7;
  float gc = g[b * 128 + c];
  float s = 0.f;
  int r0 = chunk * 32;
  const float* base = ef + ((size_t)b * 2304 + q * 576 + r0) * 128 + c;
  for (int r = half; r < 32; r += 2) s = fmaf(base[(size_t)r * 128], gc, s);
#pragma unroll
  for (int off = 32; off > 0; off >>= 1) s += __shfl_down(s, off, 64);
  __shared__ float t1[4];
  int lane = threadIdx.x & 63, wv = threadIdx.x >> 6;
  if (lane == 0) t1[wv] = s;
  __syncthreads();
  if (threadIdx.x == 0) atomicAdd(&acc[bq], t1[0] + t1[1] + t1[2] + t1[3]);
}
__global__ void k_gatefin(const float* acc, float* gates) {
  int i = threadIdx.x;
  if (i >= 8) return;
  float a = acc[i] / sqrtf(73728.0f);
  gates[i] = 1.f / (1.f + expf(-a));
}

// ---------------- im2col (gated, tap-major k) -> bf16 col [g][n][kk*128+c] ----------------
__global__ __launch_bounds__(256) void k_im2col(const float* ef, const float* gates, u16* col) {
  int idx = blockIdx.x * 256 + threadIdx.x;  // (g*576+n)*9+kk
  if (idx >= 8 * 576 * 9) return;
  int kk = idx % 9;
  int gn = idx / 9;
  int n = gn % 576, g = gn / 576;
  int b = g >> 2, q = g & 3;
  int h = n / 24 + kk / 3 - 1, w = n % 24 + kk % 3 - 1;
  u16* cp = col + (size_t)gn * 1152 + kk * 128;
  if (h < 0 || h > 23 || w < 0 || w > 23) {
    ushort4 z = {0, 0, 0, 0};
#pragma unroll
    for (int c4 = 0; c4 < 32; c4++) *(ushort4*)&cp[c4 * 4] = z;
    return;
  }
  float gt = gates[g];
  const float* ep = ef + ((size_t)b * 2304 + q * 576 + h * 24 + w) * 128;
  for (int c4 = 0; c4 < 32; c4++) {
    f32x4 v = *(const f32x4*)&ep[c4 * 4];
    ushort4 r;
    r.x = f2bf(v[0] * gt); r.y = f2bf(v[1] * gt);
    r.z = f2bf(v[2] * gt); r.w = f2bf(v[3] * gt);
    *(ushort4*)&cp[c4 * 4] = r;
  }
}

// ---------------- host ----------------
extern "C" void kernel_launch(void* const* d_in, const int* in_sizes, int n_in,
                              void* d_out, int out_size, void* d_ws, size_t ws_size,
                              hipStream_t stream) {
  if (ws_size < WS_TOTAL) return;
  char* ws = (char*)d_ws;
  u16* WB = (u16*)(ws + OB_WBF);
  float* WPE = (float*)(ws + OB_WPE);
  float* STB = (float*)(ws + OB_ST);
  float* GV = (float*)(ws + OB_GV);
  float* GT = (float*)(ws + OB_GT);
  float* GACC = (float*)(ws + OB_GACC);
  u16* CATB = (u16*)(ws + OB_CAT);
  float* YA = (float*)(ws + OB_YA);
  u16* XBF = (u16*)(ws + OB_U1);
  float* A1F = (float*)(ws + OB_U1);
  u16* QKVB = (u16*)(ws + OB_U2);
  u16* COLB = (u16*)(ws + OB_U2);
  float* EF = (float*)(ws + OB_U2 + 10616832);
  float* RF = (float*)(ws + OB_U3);
  u16* HB = (u16*)(ws + OB_U3);
  u16* AOB = (u16*)(ws + OB_AOB);
  u16* A1B = (u16*)(ws + OB_A1B);
  float* out = (float*)d_out;
  const float* x = (const float*)d_in[0];
  const float* guide = (const float*)d_in[1];
  const float* glw = (const float*)d_in[16];
  const float* glb = (const float*)d_in[17];

  // zero stats (24576B) + GV + GT + GACC region
  hipMemsetAsync(ws + OB_ST, 0, 25856, stream);

  {  // weights
    WPrepP p;
    const int mi[8] = {2, 4, 6, 10, 12, 14, 18, 20};
    const int sz[8] = {262144, 196608, 65536, 131072, 131072, 32768, 294912, 524288};
    int c = 0;
    for (int i = 0; i < 8; i++) {
      p.m[i] = (const float*)d_in[mi[i]];
      p.p[i] = (const float*)d_in[mi[i] + 1];
      p.cum[i] = c;
      c += sz[i];
    }
    p.cum[8] = c;
    p.out = WB;
    p.pem = (const float*)d_in[8];
    p.pep = (const float*)d_in[9];
    p.peout = WPE;
    k_wprep<<<(c + 255) / 256, 256, 0, stream>>>(p);
  }
  k_xpose<<<2304, 256, 0, stream>>>(x, XBF);

  auto gemm = [&](int bm64, size_t wOff, int O, int K, int M, int G,
                  const u16* X, long long xs, long long xadd, int lda,
                  float* Y, const float* Add, u16* Yb) {
    GemmP p;
    p.W = WB + wOff; p.X = X; p.Y = Y; p.Add = Add; p.Yb = Yb;
    p.lda = lda; p.O = O; p.K = K; p.M = M; p.G = G;
    for (int g = 0; g < 8; g++) p.xOff[g] = (long long)(g < G ? g : 0) * xs + xadd;
    if (bm64) {
      int grid = G * (O / 128) * (M / 64);
      k_gemm<64, 4, 32, 64><<<grid, 256, 0, stream>>>(p);
    } else {
      int grid = G * (O / 128) * (M / 128);
      k_gemm<128, 2, 64, 64><<<grid, 256, 0, stream>>>(p);
    }
  };
  auto stats = [&](const float* X, int si, int O, int rows) {
    float* st = STB + si * 1024;
    k_stats<<<256, 256, 0, stream>>>(X, st, O, rows);
    k_finstats<<<(O + 63) / 64, 64, 0, stream>>>(st, O, (float)rows);
  };
  auto norm = [&](const float* X, int si, int O, int G, int M, const float* Add,
                  u16* Yb, int ldyb, const long long* ybOff, float* Yf, int relu) {
    NormP p;
    p.X = X; p.st = STB + si * 1024; p.Add = Add; p.Yb = Yb; p.Yf = Yf;
    p.ldyb = ldyb; p.O = O; p.G = G; p.M = M; p.relu = relu;
    for (int g = 0; g < 8; g++) p.ybOff[g] = ybOff ? ybOff[(g < G) ? g : 0] : 0;
    long long total = (long long)G * M * (O / 4);
    k_norm<<<(int)((total + 255) / 256), 256, 0, stream>>>(p);
  };

  // cv1 -> bn relu -> cat[0:512]
  gemm(0, 0, 512, 512, 2304, 2, XBF, 2304LL * 512, 0, 512, YA, nullptr, nullptr);
  stats(YA, 0, 512, 4608);
  { long long yo[2] = {0, 2304LL * 1024};
    norm(YA, 0, 512, 2, 2304, nullptr, CATB, 1024, yo, nullptr, 1); }

  // qkv (bf16 only)
  gemm(0, 262144, 768, 256, 2304, 2, CATB, 2304LL * 1024, 256, 1024, nullptr, nullptr, QKVB);
  // MFMA flash attention
  k_attn<<<384, 256, 0, stream>>>(QKVB, AOB);
  // pe + residual
  k_pe<<<1152, 256, 0, stream>>>(CATB, WPE, RF);
  // aproj (+rf) -> a1 (f32 + bf16)
  gemm(0, 458752, 256, 256, 2304, 2, AOB, 2304LL * 256, 0, 256, A1F, RF, A1B);

  // ffn1 -> bn relu -> hb
  gemm(0, 524288, 512, 256, 2304, 2, A1B, 2304LL * 256, 0, 256, YA, nullptr, nullptr);
  stats(YA, 1, 512, 4608);
  { long long yo[2] = {0, 2304LL * 512};
    norm(YA, 1, 512, 2, 2304, nullptr, HB, 512, yo, nullptr, 1); }

  // ffn2 -> bn -> +a1 -> cat[512:768]
  gemm(0, 655360, 256, 512, 2304, 2, HB, 2304LL * 512, 0, 512, YA, nullptr, nullptr);
  stats(YA, 2, 256, 4608);
  { long long yo[2] = {512, 2304LL * 1024 + 512};
    norm(YA, 2, 256, 2, 2304, A1F, CATB, 1024, yo, nullptr, 0); }

  // ec -> bn relu -> ef (f32)
  gemm(0, 786432, 128, 256, 2304, 2, CATB, 2304LL * 1024, 512, 1024, YA, nullptr, nullptr);
  stats(YA, 3, 128, 4608);
  norm(YA, 3, 128, 2, 2304, nullptr, nullptr, 0, nullptr, EF, 1);

  // guide, gate (parallel partial + finish), im2col
  k_guide<<<256, 64, 0, stream>>>(guide, glw, glb, GV);
  k_gatepart<<<144, 256, 0, stream>>>(EF, GV, GACC);
  k_gatefin<<<1, 64, 0, stream>>>(GACC, GT);
  k_im2col<<<162, 256, 0, stream>>>(EF, GT, COLB);

  // mproj -> bn relu -> cat[768:1024]
  gemm(1, 819200, 256, 1152, 576, 8, COLB, 576LL * 1152, 0, 1152, YA, nullptr, nullptr);
  stats(YA, 4, 256, 4608);
  { long long yo[8];
    for (int g = 0; g < 8; g++)
      yo[g] = (long long)(g >> 2) * 2304 * 1024 + (long long)(g & 3) * 576 * 1024 + 768;
    norm(YA, 4, 256, 8, 576, nullptr, CATB, 1024, yo, nullptr, 1); }

  // cv2 -> bn relu -> out (transpose)
  gemm(0, 1114112, 512, 1024, 2304, 2, CATB, 2304LL * 1024, 0, 1024, YA, nullptr, nullptr);
  stats(YA, 5, 512, 4608);
  k_normT<<<2304, 256, 0, stream>>>(YA, STB + 5 * 1024, out);
}

// Round 5
// 293.986 us; speedup vs baseline: 2.8975x; 1.2332x over previous
//
#include <hip/hip_runtime.h>
#include <math.h>

typedef __bf16 bf16x8 __attribute__((ext_vector_type(8)));
typedef float f32x4 __attribute__((ext_vector_type(4)));
typedef unsigned short u16;
typedef unsigned int u32;

__device__ __forceinline__ u16 f2bf(float f) {
  u32 u = __float_as_uint(f);
  u32 r = u + 0x7FFF + ((u >> 16) & 1);
  return (u16)(r >> 16);
}
__device__ __forceinline__ float bf2f(u16 h) { return __uint_as_float(((u32)h) << 16); }

// ---------------- arena (byte offsets) ----------------
static constexpr size_t OB_WBF = 0;                       // 1,638,400 u16
static constexpr size_t OB_WPE = 3276800;                 // 2304 f32
static constexpr size_t OB_ST  = 3286016;                 // 6 x 4096B stat sums
static constexpr size_t OB_GV  = 3310592;                 // 256 f32
static constexpr size_t OB_GACC= 3311616;                 // 8 f32 gate accum
static constexpr size_t OB_CAT = 3311872;                 // bf16 [2][2304][1024]
static constexpr size_t OB_YA  = OB_CAT + 9437184;        // f32 gemm out (max 9.4MB)
static constexpr size_t OB_U1  = OB_YA + 9437184;         // xbf16 -> a1f f32 (4.7MB)
static constexpr size_t OB_U2  = OB_U1 + 4718592;         // qkv bf16 -> colb ; +ef f32
static constexpr size_t OB_U3  = OB_U2 + 14155776;        // rf f32 -> hb bf16 (4.7MB)
static constexpr size_t OB_AOB = OB_U3 + 4718592;         // attn out bf16 (2.36MB)
static constexpr size_t OB_A1B = OB_AOB + 2359296;        // a1 bf16 (2.36MB)
static constexpr size_t WS_TOTAL = OB_A1B + 2359296;      // ~50.5MB

// ---------------- weight prep: w = m*cos(p) -> bf16 (mproj tap-major remap) ----------------
struct WPrepP {
  const float* m[8]; const float* p[8];
  u16* out; const float* pem; const float* pep; float* peout;
  int cum[9];
};
__global__ __launch_bounds__(256) void k_wprep(WPrepP P) {
  int i = blockIdx.x * 256 + threadIdx.x;
  if (i < 2304) P.peout[i] = P.pem[i] * cosf(P.pep[i]);
  if (i >= P.cum[8]) return;
  int s = 0;
  while (s < 7 && i >= P.cum[s + 1]) s++;
  int j = i - P.cum[s];
  int src = j;
  if (s == 6) {  // mproj: out[o][kk*128+cc] <- in[(o*128+cc)*9+kk]
    int o = j / 1152, r = j % 1152, kk = r >> 7, cc = r & 127;
    src = (o * 128 + cc) * 9 + kk;
  }
  P.out[i] = f2bf(P.m[s][src] * cosf(P.p[s][src]));
}

// ---------------- x transpose: [b][c][q][hw] f32 -> [b][q*576+hw][c] bf16 ----------------
__global__ __launch_bounds__(256) void k_xpose(const float* x, u16* xb) {
  int bid = blockIdx.x;
  int mt = bid % 18; bid /= 18;
  int ct = bid % 16; bid /= 16;
  int q = bid & 3, b = bid >> 2;
  __shared__ float tile[32][33];
  int tj = threadIdx.x & 31, ti = threadIdx.x >> 5;
  const float* xp = x + (((size_t)(b * 512 + ct * 32) * 4 + q) * 576) + mt * 32;
#pragma unroll
  for (int ii = 0; ii < 4; ii++)
    tile[ti + ii * 8][tj] = xp[(size_t)(ti + ii * 8) * 4 * 576 + tj];
  __syncthreads();
  u16* yp = xb + ((size_t)b * 2304 + q * 576 + mt * 32) * 512 + ct * 32;
#pragma unroll
  for (int mm = 0; mm < 4; mm++)
    yp[(size_t)(mm * 8 + ti) * 512 + tj] = f2bf(tile[tj][mm * 8 + ti]);
}

// ---------------- MFMA GEMM: Y[g][m][o] = sum_k W[o][k] X[g][m][k] (+fused BN sums) --------
struct GemmP {
  const u16* W; const u16* X; float* Y; const float* Add; u16* Yb; float* St;
  long long xOff[8];
  int lda, O, K, M, G;
};

template <int BM, int NWO, int WO, int WM>
__global__ __launch_bounds__(256) void k_gemm(GemmP P) {
  constexpr int FO = WO / 16, FM = WM / 16;
  __shared__ __align__(16) char lds[16384 + BM * 128];
  const int mt = P.M / BM;
  const int ot = P.O >> 7;
  int bid = blockIdx.x;
  const int g = bid / (mt * ot);
  const int rr = bid % (mt * ot);
  const int ob = (rr / mt) << 7;
  const int mb = (rr % mt) * BM;
  const int t = threadIdx.x, lane = t & 63, wave = t >> 6;
  const int wo = (wave % NWO) * WO, wm = (wave / NWO) * WM;
  const u16* Wp = P.W + (size_t)ob * P.K;
  const u16* Xp = P.X + P.xOff[g] + (size_t)mb * P.lda;

  f32x4 acc[FO][FM] = {};

  for (int k0 = 0; k0 < P.K; k0 += 64) {
#pragma unroll
    for (int i = 0; i < 4; i++) {  // A: 128 rows x 8 kg
      int c = t + i * 256;
      int row = c >> 3, kg = c & 7;
      *(uint4*)&lds[((row << 3) + (kg ^ (row & 7))) << 4] =
          *(const uint4*)(Wp + (size_t)row * P.K + k0 + kg * 8);
    }
#pragma unroll
    for (int i = 0; i < BM * 8 / 256; i++) {  // B: BM rows x 8 kg
      int c = t + i * 256;
      int row = c >> 3, kg = c & 7;
      *(uint4*)&lds[16384 + (((row << 3) + (kg ^ (row & 7))) << 4)] =
          *(const uint4*)(Xp + (size_t)row * P.lda + k0 + kg * 8);
    }
    __syncthreads();
#pragma unroll
    for (int kk = 0; kk < 2; kk++) {
      int kgl = kk * 4 + (lane >> 4);
      bf16x8 af[FO], bfm[FM];
#pragma unroll
      for (int fo = 0; fo < FO; fo++) {
        int row = wo + fo * 16 + (lane & 15);
        af[fo] = *(bf16x8*)&lds[((row << 3) + (kgl ^ (row & 7))) << 4];
      }
#pragma unroll
      for (int fm = 0; fm < FM; fm++) {
        int row = wm + fm * 16 + (lane & 15);
        bfm[fm] = *(bf16x8*)&lds[16384 + (((row << 3) + (kgl ^ (row & 7))) << 4)];
      }
#pragma unroll
      for (int fo = 0; fo < FO; fo++)
#pragma unroll
        for (int fm = 0; fm < FM; fm++)
          acc[fo][fm] = __builtin_amdgcn_mfma_f32_16x16x32_bf16(af[fo], bfm[fm], acc[fo][fm], 0, 0, 0);
    }
    __syncthreads();
  }

  size_t ybase = (size_t)g * P.M * P.O;
#pragma unroll
  for (int fo = 0; fo < FO; fo++) {
    int ow = ob + wo + fo * 16 + ((lane >> 4) << 2);
#pragma unroll
    for (int fm = 0; fm < FM; fm++) {
      int m = mb + wm + fm * 16 + (lane & 15);
      f32x4 v = acc[fo][fm];
      size_t off = ybase + (size_t)m * P.O + ow;
      if (P.Add) v += *(const f32x4*)&P.Add[off];
      if (P.Y) *(f32x4*)&P.Y[off] = v;
      if (P.Yb) {
        ushort4 r;
        r.x = f2bf(v[0]); r.y = f2bf(v[1]); r.z = f2bf(v[2]); r.w = f2bf(v[3]);
        *(ushort4*)&P.Yb[off] = r;
      }
    }
  }

  // fused BN partial sums: per channel o, sum/sumsq over this block's m-slice
  if (P.St) {
#pragma unroll
    for (int fo = 0; fo < FO; fo++) {
      float sv[4], qv[4];
#pragma unroll
      for (int j = 0; j < 4; j++) { sv[j] = 0.f; qv[j] = 0.f; }
#pragma unroll
      for (int fm = 0; fm < FM; fm++)
#pragma unroll
        for (int j = 0; j < 4; j++) {
          float a = acc[fo][fm][j];
          sv[j] += a;
          qv[j] = fmaf(a, a, qv[j]);
        }
#pragma unroll
      for (int j = 0; j < 4; j++) {
#pragma unroll
        for (int mk = 1; mk < 16; mk <<= 1) {
          sv[j] += __shfl_xor(sv[j], mk, 64);
          qv[j] += __shfl_xor(qv[j], mk, 64);
        }
      }
      if ((lane & 15) == 0) {
        int o = ob + wo + fo * 16 + ((lane >> 4) << 2);
#pragma unroll
        for (int j = 0; j < 4; j++) {
          atomicAdd(&P.St[2 * (o + j)], sv[j]);
          atomicAdd(&P.St[2 * (o + j) + 1], qv[j]);
        }
      }
    }
  }
}

// ---------------- BN normalize from raw sums (+add, relu, opt gate accum) ----------------
struct NormP {
  const float* X; const float* st; const float* Add;
  u16* Yb; float* Yf; const float* gv; float* gacc;
  long long ybOff[8];
  int ldyb, O, G, M, relu;
  float n;
};
__global__ __launch_bounds__(256) void k_norm(NormP P) {
  int O4 = P.O >> 2;
  long long idx = (long long)blockIdx.x * 256 + threadIdx.x;
  if (idx >= (long long)P.G * P.M * O4) return;
  int c4 = (int)(idx % O4);
  long long gm = idx / O4;
  int m = (int)(gm % P.M);
  int g = (int)(gm / P.M);
  size_t off = (size_t)gm * P.O + c4 * 4;
  f32x4 v = *(const f32x4*)&P.X[off];
  float inv_n = 1.0f / P.n;
#pragma unroll
  for (int j = 0; j < 4; j++) {
    int c = c4 * 4 + j;
    float mean = P.st[2 * c] * inv_n;
    float var = P.st[2 * c + 1] * inv_n - mean * mean;
    v[j] = (v[j] - mean) * rsqrtf(var + 1e-5f);
  }
  if (P.Add) v += *(const f32x4*)&P.Add[off];
  if (P.relu) {
#pragma unroll
    for (int j = 0; j < 4; j++) v[j] = fmaxf(v[j], 0.f);
  }
  if (P.Yb) {
    ushort4 r;
    r.x = f2bf(v[0]); r.y = f2bf(v[1]); r.z = f2bf(v[2]); r.w = f2bf(v[3]);
    *(ushort4*)(P.Yb + P.ybOff[g] + (size_t)m * P.ldyb + c4 * 4) = r;
  }
  if (P.Yf) *(f32x4*)&P.Yf[off] = v;
  if (P.gacc) {  // block covers a single (g,q); accumulate e·gv
    float gs = 0.f;
#pragma unroll
    for (int j = 0; j < 4; j++) gs = fmaf(v[j], P.gv[g * 128 + c4 * 4 + j], gs);
#pragma unroll
    for (int mk = 1; mk < 64; mk <<= 1) gs += __shfl_xor(gs, mk, 64);
    __shared__ float t1[4];
    int lane = threadIdx.x & 63, wv = threadIdx.x >> 6;
    if (lane == 0) t1[wv] = gs;
    __syncthreads();
    if (threadIdx.x == 0)
      atomicAdd(&P.gacc[g * 4 + m / 576], t1[0] + t1[1] + t1[2] + t1[3]);
  }
}

// ---------------- final norm (raw sums) with transpose to [b][o][q][hw] f32 ----------------
__global__ __launch_bounds__(256) void k_normT(const float* X, const float* st, float* out) {
  int idx = blockIdx.x * 256 + threadIdx.x;  // (b*512+o)*576 + m4
  if (idx >= 2 * 512 * 576) return;
  int m4 = idx % 576;
  int bo = idx / 576;
  int o = bo & 511, b = bo >> 9;
  float inv_n = 1.0f / 4608.0f;
  float mean = st[2 * o] * inv_n;
  float var = st[2 * o + 1] * inv_n - mean * mean;
  float rs = rsqrtf(var + 1e-5f);
  f32x4 v;
#pragma unroll
  for (int j = 0; j < 4; j++) {
    float x = X[((size_t)b * 2304 + m4 * 4 + j) * 512 + o];
    v[j] = fmaxf((x - mean) * rs, 0.f);
  }
  *(f32x4*)&out[(size_t)bo * 2304 + m4 * 4] = v;
}

// ---------------- depthwise 3x3 pe + residual: rf[g][m][c] = dw(b)+b ----------------
__global__ __launch_bounds__(256) void k_pe(const u16* catb, const float* wpe, float* rf) {
  int idx = blockIdx.x * 256 + threadIdx.x;  // (g*2304+m)*64 + c4
  if (idx >= 2 * 2304 * 64) return;
  int c4 = idx & 63;
  int gm = idx >> 6;
  int m = gm % 2304, g = gm / 2304;
  int q = m / 576, hw = m % 576, h = hw / 24, w = hw % 24;
  const u16* base = catb + (size_t)g * 2304 * 1024 + 256 + c4 * 4;
  float acc[4];
  {
    ushort4 cv = *(const ushort4*)(base + (size_t)m * 1024);
    acc[0] = bf2f(cv.x); acc[1] = bf2f(cv.y); acc[2] = bf2f(cv.z); acc[3] = bf2f(cv.w);
  }
#pragma unroll
  for (int kh = 0; kh < 3; kh++) {
    int hh = h + kh - 1;
    if (hh < 0 || hh > 23) continue;
#pragma unroll
    for (int kw = 0; kw < 3; kw++) {
      int ww = w + kw - 1;
      if (ww < 0 || ww > 23) continue;
      ushort4 cv = *(const ushort4*)(base + (size_t)(q * 576 + hh * 24 + ww) * 1024);
      float tap[4] = {bf2f(cv.x), bf2f(cv.y), bf2f(cv.z), bf2f(cv.w)};
#pragma unroll
      for (int j = 0; j < 4; j++)
        acc[j] = fmaf(wpe[(c4 * 4 + j) * 9 + kh * 3 + kw], tap[j], acc[j]);
    }
  }
  f32x4 v = {acc[0], acc[1], acc[2], acc[3]};
  *(f32x4*)&rf[(size_t)gm * 256 + c4 * 4] = v;
}

// ---------------- MFMA flash attention (no-max softmax; scores tiny) ----------------
__global__ __launch_bounds__(256) void k_attn(const u16* qkv, u16* ao) {
  int bid = blockIdx.x;
  int tq = bid % 3; int u = bid / 3;
  int qd = u & 3; u >>= 2;
  int head = u & 15, b = u >> 4;
  int t = threadIdx.x, lane = t & 63, wv = t >> 6;
  int g = lane >> 4, q = lane & 15;
  size_t tok0 = (size_t)b * 2304 + qd * 576;
  const u16* QKV = qkv + tok0 * 768;

  __shared__ __align__(16) char shm[50176];
  u16* Kl = (u16*)(shm);                       // [576][24]
  u16* VT = (u16*)(shm + 27648);               // [(m>>3)][d][m&7]
  u16* Pl = (u16*)(shm + 46080 + wv * 1024);   // [4][16][8]

  for (int i = t; i < 1152; i += 256) {
    int m = i >> 1, half = i & 1;
    const u16* src = QKV + (size_t)m * 768 + 256 + head * 16 + half * 8;
    u16 tmp[8];
    *(uint4*)tmp = *(const uint4*)src;
    ushort4 lo, hi;
    lo.x = f2bf(bf2f(tmp[0]) * 0.25f); lo.y = f2bf(bf2f(tmp[1]) * 0.25f);
    lo.z = f2bf(bf2f(tmp[2]) * 0.25f); lo.w = f2bf(bf2f(tmp[3]) * 0.25f);
    hi.x = f2bf(bf2f(tmp[4]) * 0.25f); hi.y = f2bf(bf2f(tmp[5]) * 0.25f);
    hi.z = f2bf(bf2f(tmp[6]) * 0.25f); hi.w = f2bf(bf2f(tmp[7]) * 0.25f);
    u16* dst = Kl + m * 24 + half * 8;
    *(ushort4*)dst = lo;
    *(ushort4*)(dst + 4) = hi;
  }
  for (int mm = t; mm < 576; mm += 256) {
    const u16* src = QKV + (size_t)mm * 768 + 512 + head * 16;
    u16 tmp[16];
    *(uint4*)tmp = *(const uint4*)src;
    *(uint4*)(tmp + 8) = *(const uint4*)(src + 8);
    u16* dst = VT + (mm >> 3) * 128 + (mm & 7);
#pragma unroll
    for (int d = 0; d < 16; d++) dst[d * 8] = tmp[d];
  }
  __syncthreads();

#pragma unroll 1
  for (int i = 0; i < 3; i++) {
    int tl = wv * 3 + i;
    int qbase = tq * 192 + tl * 16;
    bf16x8 qf = {};
    if (g < 2)
      qf = *(const bf16x8*)(QKV + (size_t)(qbase + q) * 768 + head * 16 + g * 8);

    f32x4 acc_o = {};
    float ssum = 0.f;

    for (int ch = 0; ch < 18; ch++) {
      int m0 = ch * 32;
      f32x4 s[2];
#pragma unroll
      for (int h = 0; h < 2; h++) {
        bf16x8 kf = {};
        if (g < 2)
          kf = *(const bf16x8*)(Kl + (size_t)(m0 + h * 16 + q) * 24 + g * 8);
        f32x4 z = {};
        s[h] = __builtin_amdgcn_mfma_f32_16x16x32_bf16(kf, qf, z, 0, 0, 0);
      }
#pragma unroll
      for (int h = 0; h < 2; h++) {
        float p0 = __expf(s[h][0]);
        float p1 = __expf(s[h][1]);
        float p2 = __expf(s[h][2]);
        float p3 = __expf(s[h][3]);
        ssum += (p0 + p1) + (p2 + p3);
        ushort4 w;
        w.x = f2bf(p0); w.y = f2bf(p1); w.z = f2bf(p2); w.w = f2bf(p3);
        *(ushort4*)(Pl + ((h * 2 + (g >> 1)) * 16 + q) * 8 + (g & 1) * 4) = w;
      }
      bf16x8 va = *(const bf16x8*)(VT + ((m0 >> 3) + g) * 128 + q * 8);
      bf16x8 pa = *(const bf16x8*)(Pl + (g * 16 + q) * 8);
      acc_o = __builtin_amdgcn_mfma_f32_16x16x32_bf16(va, pa, acc_o, 0, 0, 0);
    }

    ssum += __shfl_xor(ssum, 16, 64);
    ssum += __shfl_xor(ssum, 32, 64);
    float inv = 1.f / ssum;
    u16* op = ao + (tok0 + qbase + q) * 256 + head * 16 + g * 4;
    ushort4 r;
    r.x = f2bf(acc_o[0] * inv);
    r.y = f2bf(acc_o[1] * inv);
    r.z = f2bf(acc_o[2] * inv);
    r.w = f2bf(acc_o[3] * inv);
    *(ushort4*)op = r;
  }
}

// ---------------- guide linear: one block per (b,e), 64-lane dot ----------------
__global__ __launch_bounds__(64) void k_guide(const float* guide, const float* glw,
                                              const float* glb, float* g) {
  int be = blockIdx.x;  // b*128+e
  int b = be >> 7, e = be & 127;
  const float* gr = guide + b * 512;
  const float* wr = glw + e * 512;
  float s = 0.f;
  for (int c = threadIdx.x; c < 512; c += 64) s = fmaf(gr[c], wr[c], s);
#pragma unroll
  for (int off = 32; off > 0; off >>= 1) s += __shfl_down(s, off, 64);
  if (threadIdx.x == 0) g[be] = s + glb[e];
}

// ---------------- im2col (gated, sigmoid inline, tap-major k) -> bf16 col ----------------
__global__ __launch_bounds__(256) void k_im2col(const float* ef, const float* gacc, u16* col) {
  int idx = blockIdx.x * 256 + threadIdx.x;  // (g*576+n)*9+kk
  if (idx >= 8 * 576 * 9) return;
  int kk = idx % 9;
  int gn = idx / 9;
  int n = gn % 576, g = gn / 576;
  int b = g >> 2, q = g & 3;
  int h = n / 24 + kk / 3 - 1, w = n % 24 + kk % 3 - 1;
  u16* cp = col + (size_t)gn * 1152 + kk * 128;
  if (h < 0 || h > 23 || w < 0 || w > 23) {
    ushort4 z = {0, 0, 0, 0};
#pragma unroll
    for (int c4 = 0; c4 < 32; c4++) *(ushort4*)&cp[c4 * 4] = z;
    return;
  }
  float a = gacc[g] / sqrtf(73728.0f);
  float gt = 1.f / (1.f + expf(-a));
  const float* ep = ef + ((size_t)b * 2304 + q * 576 + h * 24 + w) * 128;
  for (int c4 = 0; c4 < 32; c4++) {
    f32x4 v = *(const f32x4*)&ep[c4 * 4];
    ushort4 r;
    r.x = f2bf(v[0] * gt); r.y = f2bf(v[1] * gt);
    r.z = f2bf(v[2] * gt); r.w = f2bf(v[3] * gt);
    *(ushort4*)&cp[c4 * 4] = r;
  }
}

// ---------------- host ----------------
extern "C" void kernel_launch(void* const* d_in, const int* in_sizes, int n_in,
                              void* d_out, int out_size, void* d_ws, size_t ws_size,
                              hipStream_t stream) {
  if (ws_size < WS_TOTAL) return;
  char* ws = (char*)d_ws;
  u16* WB = (u16*)(ws + OB_WBF);
  float* WPE = (float*)(ws + OB_WPE);
  float* STB = (float*)(ws + OB_ST);
  float* GV = (float*)(ws + OB_GV);
  float* GACC = (float*)(ws + OB_GACC);
  u16* CATB = (u16*)(ws + OB_CAT);
  float* YA = (float*)(ws + OB_YA);
  u16* XBF = (u16*)(ws + OB_U1);
  float* A1F = (float*)(ws + OB_U1);
  u16* QKVB = (u16*)(ws + OB_U2);
  u16* COLB = (u16*)(ws + OB_U2);
  float* EF = (float*)(ws + OB_U2 + 10616832);
  float* RF = (float*)(ws + OB_U3);
  u16* HB = (u16*)(ws + OB_U3);
  u16* AOB = (u16*)(ws + OB_AOB);
  u16* A1B = (u16*)(ws + OB_A1B);
  float* out = (float*)d_out;
  const float* x = (const float*)d_in[0];
  const float* guide = (const float*)d_in[1];
  const float* glw = (const float*)d_in[16];
  const float* glb = (const float*)d_in[17];

  // zero stat sums + GV + GACC
  hipMemsetAsync(ws + OB_ST, 0, OB_CAT - OB_ST, stream);

  {  // weights
    WPrepP p;
    const int mi[8] = {2, 4, 6, 10, 12, 14, 18, 20};
    const int sz[8] = {262144, 196608, 65536, 131072, 131072, 32768, 294912, 524288};
    int c = 0;
    for (int i = 0; i < 8; i++) {
      p.m[i] = (const float*)d_in[mi[i]];
      p.p[i] = (const float*)d_in[mi[i] + 1];
      p.cum[i] = c;
      c += sz[i];
    }
    p.cum[8] = c;
    p.out = WB;
    p.pem = (const float*)d_in[8];
    p.pep = (const float*)d_in[9];
    p.peout = WPE;
    k_wprep<<<(c + 255) / 256, 256, 0, stream>>>(p);
  }
  k_guide<<<256, 64, 0, stream>>>(guide, glw, glb, GV);
  k_xpose<<<2304, 256, 0, stream>>>(x, XBF);

  auto gemm = [&](size_t wOff, int O, int K, int M, int G,
                  const u16* X, long long xs, long long xadd, int lda,
                  float* Y, const float* Add, u16* Yb, int si) {
    GemmP p;
    p.W = WB + wOff; p.X = X; p.Y = Y; p.Add = Add; p.Yb = Yb;
    p.St = (si >= 0) ? (STB + si * 1024) : nullptr;
    p.lda = lda; p.O = O; p.K = K; p.M = M; p.G = G;
    for (int g = 0; g < 8; g++) p.xOff[g] = (long long)(g < G ? g : 0) * xs + xadd;
    int grid = G * (O / 128) * (M / 64);
    k_gemm<64, 4, 32, 64><<<grid, 256, 0, stream>>>(p);
  };
  auto norm = [&](const float* X, int si, int O, int G, int M, const float* Add,
                  u16* Yb, int ldyb, const long long* ybOff, float* Yf, int relu,
                  const float* gv, float* gacc) {
    NormP p;
    p.X = X; p.st = STB + si * 1024; p.Add = Add; p.Yb = Yb; p.Yf = Yf;
    p.gv = gv; p.gacc = gacc;
    p.ldyb = ldyb; p.O = O; p.G = G; p.M = M; p.relu = relu;
    p.n = (float)(G * M);
    for (int g = 0; g < 8; g++) p.ybOff[g] = ybOff ? ybOff[(g < G) ? g : 0] : 0;
    long long total = (long long)G * M * (O / 4);
    k_norm<<<(int)((total + 255) / 256), 256, 0, stream>>>(p);
  };

  // cv1 -> bn relu -> cat[0:512]
  gemm(0, 512, 512, 2304, 2, XBF, 2304LL * 512, 0, 512, YA, nullptr, nullptr, 0);
  { long long yo[2] = {0, 2304LL * 1024};
    norm(YA, 0, 512, 2, 2304, nullptr, CATB, 1024, yo, nullptr, 1, nullptr, nullptr); }

  // qkv (bf16 only)
  gemm(262144, 768, 256, 2304, 2, CATB, 2304LL * 1024, 256, 1024, nullptr, nullptr, QKVB, -1);
  // MFMA flash attention
  k_attn<<<384, 256, 0, stream>>>(QKVB, AOB);
  // pe + residual
  k_pe<<<1152, 256, 0, stream>>>(CATB, WPE, RF);
  // aproj (+rf) -> a1 (f32 + bf16)
  gemm(458752, 256, 256, 2304, 2, AOB, 2304LL * 256, 0, 256, A1F, RF, A1B, -1);

  // ffn1 -> bn relu -> hb
  gemm(524288, 512, 256, 2304, 2, A1B, 2304LL * 256, 0, 256, YA, nullptr, nullptr, 1);
  { long long yo[2] = {0, 2304LL * 512};
    norm(YA, 1, 512, 2, 2304, nullptr, HB, 512, yo, nullptr, 1, nullptr, nullptr); }

  // ffn2 -> bn -> +a1 -> cat[512:768]
  gemm(655360, 256, 512, 2304, 2, HB, 2304LL * 512, 0, 512, YA, nullptr, nullptr, 2);
  { long long yo[2] = {512, 2304LL * 1024 + 512};
    norm(YA, 2, 256, 2, 2304, A1F, CATB, 1024, yo, nullptr, 0, nullptr, nullptr); }

  // ec -> bn relu -> ef (f32) + fused gate partials
  gemm(786432, 128, 256, 2304, 2, CATB, 2304LL * 1024, 512, 1024, YA, nullptr, nullptr, 3);
  norm(YA, 3, 128, 2, 2304, nullptr, nullptr, 0, nullptr, EF, 1, GV, GACC);

  // im2col (sigmoid inline)
  k_im2col<<<162, 256, 0, stream>>>(EF, GACC, COLB);

  // mproj -> bn relu -> cat[768:1024]
  gemm(819200, 256, 1152, 576, 8, COLB, 576LL * 1152, 0, 1152, YA, nullptr, nullptr, 4);
  { long long yo[8];
    for (int g = 0; g < 8; g++)
      yo[g] = (long long)(g >> 2) * 2304 * 1024 + (long long)(g & 3) * 576 * 1024 + 768;
    norm(YA, 4, 256, 8, 576, nullptr, CATB, 1024, yo, nullptr, 1, nullptr, nullptr); }

  // cv2 -> bn relu -> out (transpose)
  gemm(1114112, 512, 1024, 2304, 2, CATB, 2304LL * 1024, 0, 1024, YA, nullptr, nullptr, 5);
  k_normT<<<2304, 256, 0, stream>>>(YA, STB + 5 * 1024, out);
}